// Round 6
// baseline (838.237 us; speedup 1.0000x reference)
//
#include <hip/hip_runtime.h>
#include <math.h>

#define NT 256

typedef __attribute__((ext_vector_type(8))) short short8;
typedef __attribute__((ext_vector_type(4))) float float4v;

struct P28 {
    const float *h_V, *h_M;
    const int *mask_V, *mask_attend;
    const float *w1h,*w1s,*b1,*w1v;
    const float *w2h,*w2s,*b2,*w2v;
    const float *w3h,*w3s,*b3,*w3v;
    const float *d1h,*d1s,*db1,*d1v;
    const float *d2h,*d2s,*db2,*d2v;
    const float *g1,*be1,*g2,*be2;
    float *out, *dh;
    short *wt1, *wt2, *wt3;   // bf16 [n][Kpad] weight layouts in d_ws
};

__device__ inline short f2bf(float f) {
    union { float f; unsigned u; } v; v.f = f;
    unsigned r = (v.u + 0x7FFFu + ((v.u >> 16) & 1u)) >> 16;   // RNE
    return (short)r;
}

// ---------------------------------------------------------------------------
// fp32 tiled GEMM (VALU) with LDS B staging — EDGE KERNEL ONLY (byte-identical
// to the verified round-0 version).
// ---------------------------------------------------------------------------
__device__ void gemm(const float* A0, int split, const float* A1, int KA,
                     const float* uni, int uniK,
                     const float* Bg, int ldB, int N,
                     const float* bias, bool relu,
                     float* outL, int MP, float* Bbuf, int bbf, int tid)
{
    const bool vec = ((N & 3) == 0) && ((ldB & 3) == 0);
    const int Npad = vec ? N : ((N + 3) & ~3);
    const int EQ = MP >> 2;
    const int npairs = EQ * (Npad >> 2);
    const int Ktot = uniK + KA;
    int KC = bbf / Npad;
    if (KC > Ktot) KC = Ktot;

    const bool active = tid < npairs;
    const int e0 = (active ? (tid % EQ) : 0) * 4;
    const int j0 = (active ? (tid / EQ) : 0) * 4;

    float c00=0.f,c01=0.f,c02=0.f,c03=0.f;
    float c10=0.f,c11=0.f,c12=0.f,c13=0.f;
    float c20=0.f,c21=0.f,c22=0.f,c23=0.f;
    float c30=0.f,c31=0.f,c32=0.f,c33=0.f;
    float su0=0.f,su1=0.f,su2=0.f,su3=0.f;

    float4 r0, r1, r2, r3;
    r0.x=r0.y=r0.z=r0.w=0.f; r1=r0; r2=r0; r3=r0;

    if (vec) {
        int kc0 = (KC < Ktot) ? KC : Ktot;
        int nf4 = (kc0 * N) >> 2;
        int f4 = tid;
        if (f4 < nf4) { int f = f4*4; int k = f / N; r0 = *(const float4*)(Bg + (size_t)k*ldB + (f - k*N)); }
        f4 = tid + NT;
        if (f4 < nf4) { int f = f4*4; int k = f / N; r1 = *(const float4*)(Bg + (size_t)k*ldB + (f - k*N)); }
        f4 = tid + 2*NT;
        if (f4 < nf4) { int f = f4*4; int k = f / N; r2 = *(const float4*)(Bg + (size_t)k*ldB + (f - k*N)); }
        f4 = tid + 3*NT;
        if (f4 < nf4) { int f = f4*4; int k = f / N; r3 = *(const float4*)(Bg + (size_t)k*ldB + (f - k*N)); }
    }

    for (int k0 = 0; k0 < Ktot; k0 += KC) {
        int kc = Ktot - k0; if (kc > KC) kc = KC;
        __syncthreads();
        if (vec) {
            int nf4 = (kc * N) >> 2;
            float4* Bb4 = (float4*)Bbuf;
            if (tid        < nf4) Bb4[tid]        = r0;
            if (tid +   NT < nf4) Bb4[tid +   NT] = r1;
            if (tid + 2*NT < nf4) Bb4[tid + 2*NT] = r2;
            if (tid + 3*NT < nf4) Bb4[tid + 3*NT] = r3;
            int k0n = k0 + KC;
            if (k0n < Ktot) {
                int kcn = Ktot - k0n; if (kcn > KC) kcn = KC;
                int nf4n = (kcn * N) >> 2;
                const float* Bn = Bg + (size_t)k0n * ldB;
                int f4 = tid;
                if (f4 < nf4n) { int f = f4*4; int k = f / N; r0 = *(const float4*)(Bn + (size_t)k*ldB + (f - k*N)); }
                f4 = tid + NT;
                if (f4 < nf4n) { int f = f4*4; int k = f / N; r1 = *(const float4*)(Bn + (size_t)k*ldB + (f - k*N)); }
                f4 = tid + 2*NT;
                if (f4 < nf4n) { int f = f4*4; int k = f / N; r2 = *(const float4*)(Bn + (size_t)k*ldB + (f - k*N)); }
                f4 = tid + 3*NT;
                if (f4 < nf4n) { int f = f4*4; int k = f / N; r3 = *(const float4*)(Bn + (size_t)k*ldB + (f - k*N)); }
            }
        } else {
            for (int idx = tid; idx < kc * Npad; idx += NT) {
                int k = idx / Npad, j = idx - k * Npad;
                Bbuf[idx] = (j < N) ? Bg[(size_t)(k0 + k) * ldB + j] : 0.f;
            }
        }
        __syncthreads();
        if (active) {
            for (int k = 0; k < kc; ++k) {
                int kg = k0 + k;
                float4 b4 = *(const float4*)(Bbuf + k * Npad + j0);
                if (kg < uniK) {
                    float u = uni[kg];
                    su0 = fmaf(u, b4.x, su0); su1 = fmaf(u, b4.y, su1);
                    su2 = fmaf(u, b4.z, su2); su3 = fmaf(u, b4.w, su3);
                } else {
                    int ka = kg - uniK;
                    const float* arow = (ka < split) ? (A0 + (size_t)ka * MP + e0)
                                                     : (A1 + (size_t)(ka - split) * MP + e0);
                    float4 a4 = *(const float4*)arow;
                    c00 = fmaf(a4.x, b4.x, c00); c01 = fmaf(a4.y, b4.x, c01);
                    c02 = fmaf(a4.z, b4.x, c02); c03 = fmaf(a4.w, b4.x, c03);
                    c10 = fmaf(a4.x, b4.y, c10); c11 = fmaf(a4.y, b4.y, c11);
                    c12 = fmaf(a4.z, b4.y, c12); c13 = fmaf(a4.w, b4.y, c13);
                    c20 = fmaf(a4.x, b4.z, c20); c21 = fmaf(a4.y, b4.z, c21);
                    c22 = fmaf(a4.z, b4.z, c22); c23 = fmaf(a4.w, b4.z, c23);
                    c30 = fmaf(a4.x, b4.w, c30); c31 = fmaf(a4.y, b4.w, c31);
                    c32 = fmaf(a4.z, b4.w, c32); c33 = fmaf(a4.w, b4.w, c33);
                }
            }
        }
    }
    __syncthreads();
    if (active) {
        float4 o;
        if (j0 + 0 < N) {
            float s = su0 + (bias ? bias[j0 + 0] : 0.f);
            o.x = c00 + s; o.y = c01 + s; o.z = c02 + s; o.w = c03 + s;
            if (relu) { o.x = fmaxf(o.x,0.f); o.y = fmaxf(o.y,0.f); o.z = fmaxf(o.z,0.f); o.w = fmaxf(o.w,0.f); }
            *(float4*)(outL + (size_t)(j0 + 0) * MP + e0) = o;
        }
        if (j0 + 1 < N) {
            float s = su1 + (bias ? bias[j0 + 1] : 0.f);
            o.x = c10 + s; o.y = c11 + s; o.z = c12 + s; o.w = c13 + s;
            if (relu) { o.x = fmaxf(o.x,0.f); o.y = fmaxf(o.y,0.f); o.z = fmaxf(o.z,0.f); o.w = fmaxf(o.w,0.f); }
            *(float4*)(outL + (size_t)(j0 + 1) * MP + e0) = o;
        }
        if (j0 + 2 < N) {
            float s = su2 + (bias ? bias[j0 + 2] : 0.f);
            o.x = c20 + s; o.y = c21 + s; o.z = c22 + s; o.w = c23 + s;
            if (relu) { o.x = fmaxf(o.x,0.f); o.y = fmaxf(o.y,0.f); o.z = fmaxf(o.z,0.f); o.w = fmaxf(o.w,0.f); }
            *(float4*)(outL + (size_t)(j0 + 2) * MP + e0) = o;
        }
        if (j0 + 3 < N) {
            float s = su3 + (bias ? bias[j0 + 3] : 0.f);
            o.x = c30 + s; o.y = c31 + s; o.z = c32 + s; o.w = c33 + s;
            if (relu) { o.x = fmaxf(o.x,0.f); o.y = fmaxf(o.y,0.f); o.z = fmaxf(o.z,0.f); o.w = fmaxf(o.w,0.f); }
            *(float4*)(outL + (size_t)(j0 + 3) * MP + e0) = o;
        }
    }
}

// ---------------------------------------------------------------------------
// Direct-B fp32 GEMM — NODE KERNEL. Single contiguous A in LDS; B read
// straight from global (weights L1/L2-hot; 4 threads broadcast-share each
// float4 row segment). Requires N%4==0 && ldB%4==0. One internal barrier
// before stores (so outL may alias A). A must be fenced before the call.
// ---------------------------------------------------------------------------
__device__ void gemm_d(const float* A, int Ktot,
                       const float* Bg, int ldB, int N,
                       const float* bias, bool relu,
                       float* outL, int MP, int tid)
{
    const int EQ = MP >> 2;
    const int npairs = EQ * (N >> 2);
    const bool active = tid < npairs;
    const int e0 = (active ? (tid % EQ) : 0) * 4;
    const int j0 = (active ? (tid / EQ) : 0) * 4;

    float c00=0.f,c01=0.f,c02=0.f,c03=0.f;
    float c10=0.f,c11=0.f,c12=0.f,c13=0.f;
    float c20=0.f,c21=0.f,c22=0.f,c23=0.f;
    float c30=0.f,c31=0.f,c32=0.f,c33=0.f;

    if (active) {
        for (int k = 0; k < Ktot; ++k) {
            float4 a4 = *(const float4*)(A + (size_t)k * MP + e0);
            float4 b4 = *(const float4*)(Bg + (size_t)k * ldB + j0);
            c00 = fmaf(a4.x, b4.x, c00); c01 = fmaf(a4.y, b4.x, c01);
            c02 = fmaf(a4.z, b4.x, c02); c03 = fmaf(a4.w, b4.x, c03);
            c10 = fmaf(a4.x, b4.y, c10); c11 = fmaf(a4.y, b4.y, c11);
            c12 = fmaf(a4.z, b4.y, c12); c13 = fmaf(a4.w, b4.y, c13);
            c20 = fmaf(a4.x, b4.z, c20); c21 = fmaf(a4.y, b4.z, c21);
            c22 = fmaf(a4.z, b4.z, c22); c23 = fmaf(a4.w, b4.z, c23);
            c30 = fmaf(a4.x, b4.w, c30); c31 = fmaf(a4.y, b4.w, c31);
            c32 = fmaf(a4.z, b4.w, c32); c33 = fmaf(a4.w, b4.w, c33);
        }
    }
    __syncthreads();
    if (active) {
        float4 o;
        float s0 = bias ? bias[j0 + 0] : 0.f;
        o.x = c00 + s0; o.y = c01 + s0; o.z = c02 + s0; o.w = c03 + s0;
        if (relu) { o.x = fmaxf(o.x,0.f); o.y = fmaxf(o.y,0.f); o.z = fmaxf(o.z,0.f); o.w = fmaxf(o.w,0.f); }
        *(float4*)(outL + (size_t)(j0 + 0) * MP + e0) = o;
        float s1 = bias ? bias[j0 + 1] : 0.f;
        o.x = c10 + s1; o.y = c11 + s1; o.z = c12 + s1; o.w = c13 + s1;
        if (relu) { o.x = fmaxf(o.x,0.f); o.y = fmaxf(o.y,0.f); o.z = fmaxf(o.z,0.f); o.w = fmaxf(o.w,0.f); }
        *(float4*)(outL + (size_t)(j0 + 1) * MP + e0) = o;
        float s2 = bias ? bias[j0 + 2] : 0.f;
        o.x = c20 + s2; o.y = c21 + s2; o.z = c22 + s2; o.w = c23 + s2;
        if (relu) { o.x = fmaxf(o.x,0.f); o.y = fmaxf(o.y,0.f); o.z = fmaxf(o.z,0.f); o.w = fmaxf(o.w,0.f); }
        *(float4*)(outL + (size_t)(j0 + 2) * MP + e0) = o;
        float s3 = bias ? bias[j0 + 3] : 0.f;
        o.x = c30 + s3; o.y = c31 + s3; o.z = c32 + s3; o.w = c33 + s3;
        if (relu) { o.x = fmaxf(o.x,0.f); o.y = fmaxf(o.y,0.f); o.z = fmaxf(o.z,0.f); o.w = fmaxf(o.w,0.f); }
        *(float4*)(outL + (size_t)(j0 + 3) * MP + e0) = o;
    }
}

__device__ void vn_dev(const float* vh, int nch, int MP, int cs,
                       float* out, int ostr, int tid)
{
    for (int idx = tid; idx < nch * cs; idx += NT) {
        int h = idx / cs, e = idx - h * cs;
        float a = vh[h * MP + e], b = vh[h * MP + cs + e], c = vh[h * MP + 2 * cs + e];
        out[h * ostr + e] = sqrtf(fmaxf(a * a + b * b + c * c, 1e-8f));
    }
}

__device__ void gate_dev(float* vb, int nch, int MP, int cs, int tid)
{
    for (int idx = tid; idx < nch * cs; idx += NT) {
        int o = idx / cs, e = idx - o * cs;
        float* b = vb + o * MP + e;
        float a = b[0], b1 = b[cs], c = b[2 * cs];
        float n = sqrtf(fmaxf(a * a + b1 * b1 + c * c, 1e-8f));
        float g = 1.f / (1.f + expf(-n));
        b[0] = a * g; b[cs] = b1 * g; b[2 * cs] = c * g;
    }
}

// ---------------------------------------------------------------------------
// MFMA GEMM: M=32 edges, N=100 (7 n-tiles of 16, cols>=100 discarded),
// A bf16 LDS [32][Astr], B bf16 GLOBAL [112][Kpad] ([n][k], prep-transposed).
// ---------------------------------------------------------------------------
__device__ void mfma_gemm(const short* Alds, int Astr, const short* Bg, int Kpad,
                          int ktiles, const float* bias,
                          short* outA, int outAstr, float* outS, int tid)
{
    const int w = tid >> 6, lane = tid & 63;
    const int q = lane >> 4, l16 = lane & 15;
    for (int t = w; t < 14; t += 4) {
        int mt = t & 1, nt = t >> 1;
        const short* ap = Alds + (mt * 16 + l16) * Astr + q * 8;
        const short* bp = Bg + (size_t)(nt * 16 + l16) * Kpad + q * 8;
        float4v acc = {0.f, 0.f, 0.f, 0.f};
        for (int kt = 0; kt < ktiles; ++kt) {
            short8 a = *(const short8*)(ap + kt * 32);
            short8 b = *(const short8*)(bp + kt * 32);
            acc = __builtin_amdgcn_mfma_f32_16x16x32_bf16(a, b, acc, 0, 0, 0);
        }
        int j = nt * 16 + l16;
        if (j < 100) {
            float bj = bias ? bias[j] : 0.f;
            int ebase = mt * 16 + q * 4;
            for (int r = 0; r < 4; ++r) {
                float v = acc[r] + bj;
                if (outA) { v = fmaxf(v, 0.f); outA[(ebase + r) * outAstr + j] = f2bf(v); }
                else      { outS[j * 33 + (ebase + r)] = v; }
            }
        }
    }
}

// ---------------------------------------------------------------------------
// prep: transpose+convert the three s-path weight matrices to bf16 [n][Kpad].
// ---------------------------------------------------------------------------
__global__ __launch_bounds__(NT) void prep_w(P28 p)
{
    int id = blockIdx.x * NT + threadIdx.x;
    int stride = gridDim.x * NT;
    for (int i = id; i < 112 * 288; i += stride) {
        int n = i / 288, k = i - n * 288;
        float v = 0.f;
        if (n < 100) {
            int row = -1;
            if (k < 132) row = 100 + k;
            else if (k < 165) row = 232 + (k - 132);
            else if (k < 265) row = k - 165;
            if (row >= 0) v = p.w1s[(size_t)row * 100 + n];
        }
        p.wt1[i] = f2bf(v);
    }
    for (int i = id; i < 112 * 128; i += stride) {
        int n = i / 128, k = i - n * 128;
        p.wt2[i] = f2bf((n < 100 && k < 116) ? p.w2s[(size_t)k * 100 + n] : 0.f);
    }
    for (int i = id; i < 112 * 128; i += stride) {
        int n = i / 128, k = i - n * 128;
        p.wt3[i] = f2bf((n < 100 && k < 116) ? p.w3s[(size_t)k * 100 + n] : 0.f);
    }
}

// ---------------------------------------------------------------------------
// Edge kernel: one block per node; 30 edges (+2 pad). s-path on MFMA.
// (byte-identical to the verified round-0 version)
// ---------------------------------------------------------------------------
__global__ __launch_bounds__(NT) void edge_kernel(P28 p)
{
    __shared__ __align__(16) float Bbuf[1200];        //  4.8 KB (v-path weights)
    __shared__ __align__(16) short A1s[32 * 296];     // 18.9 KB GEMM1 A (bf16); aliased by A3
    __shared__ __align__(16) float bufY[3300];        // 13.2 KB vbuf -> A2 (bf16) -> S3 (fp32)
    __shared__ __align__(16) float vhb[33 * 96];      // 12.7 KB v-path fp32 ping-pong
    __shared__ float maskf[32];

    short* A3s = A1s;                 // 32*136 sh = 8.7 KB <= A1s
    short* A2s = (short*)bufY;        // 32*136 sh = 8.7 KB <= bufY
    float* vbuf = bufY;               // 33*96 f = 12.7 KB
    float* S3   = bufY;               // 100*33 f = 13.2 KB

    const int node = blockIdx.x, tid = threadIdx.x;
    const float* hV = p.h_V + (size_t)node * 148;

    for (int i = tid; i < 32; i += NT)
        maskf[i] = (i < 30) ? (float)p.mask_attend[(size_t)node * 30 + i] : 0.f;
    // A1 cols 0..131: hM scalars bf16 (coalesced over k within an e-row)
    for (int idx = tid; idx < 32 * 132; idx += NT) {
        int e = idx / 132, k = idx - e * 132;
        float v = (e < 30) ? p.h_M[((size_t)node * 30 + e) * 183 + 51 + k] : 0.f;
        A1s[e * 296 + k] = f2bf(v);
    }
    // A1 cols 165..264: hV scalars replicated over e
    for (int idx = tid; idx < 32 * 100; idx += NT) {
        int i = idx >> 5, e = idx & 31;
        A1s[e * 296 + 165 + i] = f2bf(hV[48 + i]);
    }
    // A1 cols 265..287: zero (K pad)
    for (int idx = tid; idx < 32 * 23; idx += NT) {
        int kk = idx / 32, e = idx - kk * 32;
        A1s[e * 296 + 265 + kk] = 0;
    }
    // vbuf fp32 vectors [i][c*32+e]: rows 0..15 hV (replicated), 16..32 hM
    for (int idx = tid; idx < 33 * 96; idx += NT) {
        int i = idx / 96, r = idx - i * 96, c = r >> 5, e = r & 31;
        float v = 0.f;
        if (i < 16) v = hV[c * 16 + i];
        else if (e < 30) v = p.h_M[((size_t)node * 30 + e) * 183 + c * 17 + (i - 16)];
        vbuf[idx] = v;
    }
    __syncthreads();

    // ---- GVP1 v-path: vh1 = vbuf @ w1h ----
    gemm(vbuf, 33, nullptr, 33, nullptr, 0, p.w1h, 33, 33, nullptr, false, vhb, 96, Bbuf, 1200, tid);
    __syncthreads();
    // vn1 -> A1 cols 132..164 (bf16); zero A2 pad cols 116..127 (vbuf now dead)
    for (int idx = tid; idx < 33 * 32; idx += NT) {
        int h = idx >> 5, e = idx & 31;
        float a = vhb[h * 96 + e], b = vhb[h * 96 + 32 + e], c = vhb[h * 96 + 64 + e];
        A1s[e * 296 + 132 + h] = f2bf(sqrtf(fmaxf(a * a + b * b + c * c, 1e-8f)));
    }
    for (int idx = tid; idx < 32 * 12; idx += NT) {
        int kk = idx >> 5, e = idx & 31;
        A2s[e * 136 + 116 + kk] = 0;
    }
    __syncthreads();
    // v1 = gate(vh1 @ w1v)
    gemm(vhb, 33, nullptr, 33, nullptr, 0, p.w1v, 16, 16, nullptr, false, vhb, 96, Bbuf, 1200, tid);
    __syncthreads();
    gate_dev(vhb, 16, 96, 32, tid);
    __syncthreads();
    // ---- MFMA GEMM1: s1 = relu(A1 @ wt1 + b1) -> A2 bf16 ----
    mfma_gemm(A1s, 296, p.wt1, 288, 9, p.b1, A2s, 136, nullptr, tid);
    __syncthreads();

    // ---- GVP2 v-path ----
    gemm(vhb, 16, nullptr, 16, nullptr, 0, p.w2h, 16, 16, nullptr, false, vhb + 16 * 96, 96, Bbuf, 1200, tid);
    __syncthreads();
    // vn2 -> A2 cols 100..115; zero A3 pad cols (A1 dead after GEMM1)
    for (int idx = tid; idx < 16 * 32; idx += NT) {
        int h = idx >> 5, e = idx & 31;
        float a = vhb[(16 + h) * 96 + e], b = vhb[(16 + h) * 96 + 32 + e], c = vhb[(16 + h) * 96 + 64 + e];
        A2s[e * 136 + 100 + h] = f2bf(sqrtf(fmaxf(a * a + b * b + c * c, 1e-8f)));
    }
    for (int idx = tid; idx < 32 * 12; idx += NT) {
        int kk = idx >> 5, e = idx & 31;
        A3s[e * 136 + 116 + kk] = 0;
    }
    __syncthreads();
    gemm(vhb + 16 * 96, 16, nullptr, 16, nullptr, 0, p.w2v, 16, 16, nullptr, false, vhb, 96, Bbuf, 1200, tid);
    __syncthreads();
    gate_dev(vhb, 16, 96, 32, tid);
    __syncthreads();
    // ---- MFMA GEMM2: s2 = relu(A2 @ wt2 + b2) -> A3 bf16 ----
    mfma_gemm(A2s, 136, p.wt2, 128, 4, p.b2, A3s, 136, nullptr, tid);
    __syncthreads();

    // ---- GVP3 v-path (no gate) ----
    gemm(vhb, 16, nullptr, 16, nullptr, 0, p.w3h, 16, 16, nullptr, false, vhb + 16 * 96, 96, Bbuf, 1200, tid);
    __syncthreads();
    for (int idx = tid; idx < 16 * 32; idx += NT) {
        int h = idx >> 5, e = idx & 31;
        float a = vhb[(16 + h) * 96 + e], b = vhb[(16 + h) * 96 + 32 + e], c = vhb[(16 + h) * 96 + 64 + e];
        A3s[e * 136 + 100 + h] = f2bf(sqrtf(fmaxf(a * a + b * b + c * c, 1e-8f)));
    }
    __syncthreads();
    gemm(vhb + 16 * 96, 16, nullptr, 16, nullptr, 0, p.w3v, 16, 16, nullptr, false, vhb, 96, Bbuf, 1200, tid);
    __syncthreads();
    // ---- MFMA GEMM3: s3 = A3 @ wt3 + b3 -> S3 fp32 [j][33] (A2 dead) ----
    mfma_gemm(A3s, 136, p.wt3, 128, 4, p.b3, nullptr, 0, S3, tid);
    __syncthreads();

    // ---- masked mean over 30 edges -> dh (staged in d_out) ----
    float* dhn = p.dh + (size_t)node * 148;
    for (int f = tid; f < 148; f += NT) {
        float s = 0.f;
        int e = f % 30;
        if (f < 48) {
            int c = f >> 4, o = f & 15;
            const float* src = vhb + o * 96 + c * 32;
            for (int t = 0; t < 30; ++t) { s += maskf[e] * src[e]; if (++e == 30) e = 0; }
        } else {
            const float* src = S3 + (size_t)(f - 48) * 33;
            for (int t = 0; t < 30; ++t) { s += maskf[e] * src[e]; if (++e == 30) e = 0; }
        }
        dhn[f] = s * (1.f / 30.f);
    }
}

// ---------------------------------------------------------------------------
// Node kernel v4: 8 nodes/block, 1024 blocks. Direct-B gemm_d (no Bbuf, no
// staging barriers); LDS 29,056 B -> 5 blocks/CU. LN stats kept in the
// round-3 serial tid<8 shape (ICE bisection: only gemm_d is new).
// A2n is [432][8]: rows 0..399 = d1s output, rows 400..431 = vn2 (so the
// d2s GEMM has one contiguous A).
// ---------------------------------------------------------------------------
__global__ __launch_bounds__(NT) void node_kernel(P28 p)
{
    __shared__ __align__(16) float S1n[132 * 8];   // rows 0..99 scalars, 100..131 vn1
    __shared__ __align__(16) float A2n[432 * 8];
    __shared__ __align__(16) float s2n[100 * 8];
    __shared__ __align__(16) float hvv[16 * 24];   // [i][c*8+n]
    __shared__ __align__(16) float vhA[32 * 24];
    __shared__ __align__(16) float vhB[32 * 24];
    __shared__ float mu[8], isd[8], vrm[8], mkv[8];

    const int nb = blockIdx.x * 8;
    const int tid = threadIdx.x;

    for (int idx = tid; idx < 800; idx += NT) {
        int n = idx & 7, j = idx >> 3;
        size_t g = (size_t)(nb + n) * 148 + 48 + j;
        S1n[idx] = p.h_V[g] + p.dh[g];
    }
    for (int idx = tid; idx < 384; idx += NT) {
        int i = idx / 24, r = idx - i * 24, c = r >> 3, n = r & 7;
        size_t g = (size_t)(nb + n) * 148 + c * 16 + i;
        hvv[idx] = p.h_V[g] + p.dh[g];
    }
    for (int i = tid; i < 8; i += NT) mkv[i] = (float)p.mask_V[nb + i];
    __syncthreads();

    if (tid < 8) {
        int n = tid;
        float sm = 0.f;
        for (int j = 0; j < 100; ++j) sm += S1n[j * 8 + n];
        float m = sm * 0.01f, var = 0.f;
        for (int j = 0; j < 100; ++j) { float d = S1n[j * 8 + n] - m; var += d * d; }
        mu[n] = m; isd[n] = rsqrtf(var * 0.01f + 1e-3f);
        float vm = 0.f;
        for (int i = 0; i < 16; ++i) {
            float a = hvv[i * 24 + n], b = hvv[i * 24 + 8 + n], c = hvv[i * 24 + 16 + n];
            vm += fmaxf(a * a + b * b + c * c, 1e-8f);
        }
        vrm[n] = rsqrtf(vm * (1.f / 16.f));
    }
    __syncthreads();
    for (int idx = tid; idx < 800; idx += NT) {
        int n = idx & 7, j = idx >> 3;
        S1n[idx] = (S1n[idx] - mu[n]) * isd[n] * p.g1[j] + p.be1[j];
    }
    for (int idx = tid; idx < 384; idx += NT) hvv[idx] *= vrm[idx & 7];
    __syncthreads();

    // ---- W_dh GVP1 ----
    gemm_d(hvv, 16, p.d1h, 32, 32, nullptr, false, vhA, 24, tid);
    __syncthreads();
    vn_dev(vhA, 32, 24, 8, S1n + 100 * 8, 8, tid);
    __syncthreads();
    gemm_d(S1n, 132, p.d1s, 400, 400, p.db1, true, A2n, 8, tid);
    gemm_d(vhA, 32, p.d1v, 32, 32, nullptr, false, vhB, 24, tid);
    __syncthreads();
    gate_dev(vhB, 32, 24, 8, tid);
    __syncthreads();

    // ---- W_dh GVP2 ----
    gemm_d(vhB, 32, p.d2h, 32, 32, nullptr, false, vhA, 24, tid);
    __syncthreads();
    vn_dev(vhA, 32, 24, 8, A2n + 400 * 8, 8, tid);   // vn2 -> A2n rows 400..431
    __syncthreads();
    gemm_d(A2n, 432, p.d2s, 100, 100, p.db2, false, s2n, 8, tid);
    gemm_d(vhA, 32, p.d2v, 16, 16, nullptr, false, vhB, 24, tid);
    __syncthreads();

    for (int idx = tid; idx < 800; idx += NT) s2n[idx] += S1n[idx];
    for (int idx = tid; idx < 384; idx += NT) vhB[idx] += hvv[idx];
    __syncthreads();

    if (tid < 8) {
        int n = tid;
        float sm = 0.f;
        for (int j = 0; j < 100; ++j) sm += s2n[j * 8 + n];
        float m = sm * 0.01f, var = 0.f;
        for (int j = 0; j < 100; ++j) { float d = s2n[j * 8 + n] - m; var += d * d; }
        mu[n] = m; isd[n] = rsqrtf(var * 0.01f + 1e-3f);
        float vm = 0.f;
        for (int i = 0; i < 16; ++i) {
            float a = vhB[i * 24 + n], b = vhB[i * 24 + 8 + n], c = vhB[i * 24 + 16 + n];
            vm += fmaxf(a * a + b * b + c * c, 1e-8f);
        }
        vrm[n] = rsqrtf(vm * (1.f / 16.f));
    }
    __syncthreads();
    for (int idx = tid; idx < 800; idx += NT) {
        int n = idx & 7, j = idx >> 3;
        s2n[idx] = (s2n[idx] - mu[n]) * isd[n] * p.g2[j] + p.be2[j];
    }
    for (int idx = tid; idx < 384; idx += NT) vhB[idx] *= vrm[idx & 7];
    __syncthreads();

    for (int idx = tid; idx < 8 * 148; idx += NT) {
        int n = idx / 148, f = idx - n * 148;
        float v;
        if (f < 48) { int c = f >> 4, o = f & 15; v = vhB[o * 24 + c * 8 + n]; }
        else        { v = s2n[(f - 48) * 8 + n]; }
        p.out[(size_t)(nb + n) * 148 + f] = mkv[n] * v;
    }
}

extern "C" void kernel_launch(void* const* d_in, const int* in_sizes, int n_in,
                              void* d_out, int out_size, void* d_ws, size_t ws_size,
                              hipStream_t stream)
{
    P28 p;
    p.h_V = (const float*)d_in[0];
    p.h_M = (const float*)d_in[1];
    p.mask_V = (const int*)d_in[2];
    p.mask_attend = (const int*)d_in[3];
    const float** w = (const float**)&p.w1h;
    for (int i = 0; i < 24; ++i) w[i] = (const float*)d_in[4 + i];
    p.out = (float*)d_out;
    p.dh  = (float*)d_out;              // stage dh in d_out; node kernel reads then overwrites
    p.wt1 = (short*)d_ws;               // 112*288 bf16
    p.wt2 = p.wt1 + 112 * 288;          // 112*128 bf16
    p.wt3 = p.wt2 + 112 * 128;          // 112*128 bf16

    prep_w<<<dim3(64), dim3(NT), 0, stream>>>(p);
    edge_kernel<<<dim3(8192), dim3(NT), 0, stream>>>(p);
    node_kernel<<<dim3(1024), dim3(NT), 0, stream>>>(p);
}

// Round 8
// 823.204 us; speedup vs baseline: 1.0183x; 1.0183x over previous
//
#include <hip/hip_runtime.h>
#include <math.h>

#define NT 256

typedef __attribute__((ext_vector_type(8))) short short8;
typedef __attribute__((ext_vector_type(4))) float float4v;

struct P28 {
    const float *h_V, *h_M;
    const int *mask_V, *mask_attend;
    const float *w1h,*w1s,*b1,*w1v;
    const float *w2h,*w2s,*b2,*w2v;
    const float *w3h,*w3s,*b3,*w3v;
    const float *d1h,*d1s,*db1,*d1v;
    const float *d2h,*d2s,*db2,*d2v;
    const float *g1,*be1,*g2,*be2;
    float *out, *dh;
    short *wt1, *wt2, *wt3;   // bf16 [n][Kpad] weight layouts in d_ws
    float *wp1h;              // fp32 [33][36] padded w1h in d_ws
};

__device__ inline short f2bf(float f) {
    union { float f; unsigned u; } v; v.f = f;
    unsigned r = (v.u + 0x7FFFu + ((v.u >> 16) & 1u)) >> 16;   // RNE
    return (short)r;
}

// ---------------------------------------------------------------------------
// fp32 tiled GEMM (VALU) with LDS B staging — NODE KERNEL ONLY (byte-identical
// to the verified round-0 version).
// ---------------------------------------------------------------------------
__device__ void gemm(const float* A0, int split, const float* A1, int KA,
                     const float* uni, int uniK,
                     const float* Bg, int ldB, int N,
                     const float* bias, bool relu,
                     float* outL, int MP, float* Bbuf, int bbf, int tid)
{
    const bool vec = ((N & 3) == 0) && ((ldB & 3) == 0);
    const int Npad = vec ? N : ((N + 3) & ~3);
    const int EQ = MP >> 2;
    const int npairs = EQ * (Npad >> 2);
    const int Ktot = uniK + KA;
    int KC = bbf / Npad;
    if (KC > Ktot) KC = Ktot;

    const bool active = tid < npairs;
    const int e0 = (active ? (tid % EQ) : 0) * 4;
    const int j0 = (active ? (tid / EQ) : 0) * 4;

    float c00=0.f,c01=0.f,c02=0.f,c03=0.f;
    float c10=0.f,c11=0.f,c12=0.f,c13=0.f;
    float c20=0.f,c21=0.f,c22=0.f,c23=0.f;
    float c30=0.f,c31=0.f,c32=0.f,c33=0.f;
    float su0=0.f,su1=0.f,su2=0.f,su3=0.f;

    float4 r0, r1, r2, r3;
    r0.x=r0.y=r0.z=r0.w=0.f; r1=r0; r2=r0; r3=r0;

    if (vec) {
        int kc0 = (KC < Ktot) ? KC : Ktot;
        int nf4 = (kc0 * N) >> 2;
        int f4 = tid;
        if (f4 < nf4) { int f = f4*4; int k = f / N; r0 = *(const float4*)(Bg + (size_t)k*ldB + (f - k*N)); }
        f4 = tid + NT;
        if (f4 < nf4) { int f = f4*4; int k = f / N; r1 = *(const float4*)(Bg + (size_t)k*ldB + (f - k*N)); }
        f4 = tid + 2*NT;
        if (f4 < nf4) { int f = f4*4; int k = f / N; r2 = *(const float4*)(Bg + (size_t)k*ldB + (f - k*N)); }
        f4 = tid + 3*NT;
        if (f4 < nf4) { int f = f4*4; int k = f / N; r3 = *(const float4*)(Bg + (size_t)k*ldB + (f - k*N)); }
    }

    for (int k0 = 0; k0 < Ktot; k0 += KC) {
        int kc = Ktot - k0; if (kc > KC) kc = KC;
        __syncthreads();
        if (vec) {
            int nf4 = (kc * N) >> 2;
            float4* Bb4 = (float4*)Bbuf;
            if (tid        < nf4) Bb4[tid]        = r0;
            if (tid +   NT < nf4) Bb4[tid +   NT] = r1;
            if (tid + 2*NT < nf4) Bb4[tid + 2*NT] = r2;
            if (tid + 3*NT < nf4) Bb4[tid + 3*NT] = r3;
            int k0n = k0 + KC;
            if (k0n < Ktot) {
                int kcn = Ktot - k0n; if (kcn > KC) kcn = KC;
                int nf4n = (kcn * N) >> 2;
                const float* Bn = Bg + (size_t)k0n * ldB;
                int f4 = tid;
                if (f4 < nf4n) { int f = f4*4; int k = f / N; r0 = *(const float4*)(Bn + (size_t)k*ldB + (f - k*N)); }
                f4 = tid + NT;
                if (f4 < nf4n) { int f = f4*4; int k = f / N; r1 = *(const float4*)(Bn + (size_t)k*ldB + (f - k*N)); }
                f4 = tid + 2*NT;
                if (f4 < nf4n) { int f = f4*4; int k = f / N; r2 = *(const float4*)(Bn + (size_t)k*ldB + (f - k*N)); }
                f4 = tid + 3*NT;
                if (f4 < nf4n) { int f = f4*4; int k = f / N; r3 = *(const float4*)(Bn + (size_t)k*ldB + (f - k*N)); }
            }
        } else {
            for (int idx = tid; idx < kc * Npad; idx += NT) {
                int k = idx / Npad, j = idx - k * Npad;
                Bbuf[idx] = (j < N) ? Bg[(size_t)(k0 + k) * ldB + j] : 0.f;
            }
        }
        __syncthreads();
        if (active) {
            for (int k = 0; k < kc; ++k) {
                int kg = k0 + k;
                float4 b4 = *(const float4*)(Bbuf + k * Npad + j0);
                if (kg < uniK) {
                    float u = uni[kg];
                    su0 = fmaf(u, b4.x, su0); su1 = fmaf(u, b4.y, su1);
                    su2 = fmaf(u, b4.z, su2); su3 = fmaf(u, b4.w, su3);
                } else {
                    int ka = kg - uniK;
                    const float* arow = (ka < split) ? (A0 + (size_t)ka * MP + e0)
                                                     : (A1 + (size_t)(ka - split) * MP + e0);
                    float4 a4 = *(const float4*)arow;
                    c00 = fmaf(a4.x, b4.x, c00); c01 = fmaf(a4.y, b4.x, c01);
                    c02 = fmaf(a4.z, b4.x, c02); c03 = fmaf(a4.w, b4.x, c03);
                    c10 = fmaf(a4.x, b4.y, c10); c11 = fmaf(a4.y, b4.y, c11);
                    c12 = fmaf(a4.z, b4.y, c12); c13 = fmaf(a4.w, b4.y, c13);
                    c20 = fmaf(a4.x, b4.z, c20); c21 = fmaf(a4.y, b4.z, c21);
                    c22 = fmaf(a4.z, b4.z, c22); c23 = fmaf(a4.w, b4.z, c23);
                    c30 = fmaf(a4.x, b4.w, c30); c31 = fmaf(a4.y, b4.w, c31);
                    c32 = fmaf(a4.z, b4.w, c32); c33 = fmaf(a4.w, b4.w, c33);
                }
            }
        }
    }
    __syncthreads();
    if (active) {
        float4 o;
        if (j0 + 0 < N) {
            float s = su0 + (bias ? bias[j0 + 0] : 0.f);
            o.x = c00 + s; o.y = c01 + s; o.z = c02 + s; o.w = c03 + s;
            if (relu) { o.x = fmaxf(o.x,0.f); o.y = fmaxf(o.y,0.f); o.z = fmaxf(o.z,0.f); o.w = fmaxf(o.w,0.f); }
            *(float4*)(outL + (size_t)(j0 + 0) * MP + e0) = o;
        }
        if (j0 + 1 < N) {
            float s = su1 + (bias ? bias[j0 + 1] : 0.f);
            o.x = c10 + s; o.y = c11 + s; o.z = c12 + s; o.w = c13 + s;
            if (relu) { o.x = fmaxf(o.x,0.f); o.y = fmaxf(o.y,0.f); o.z = fmaxf(o.z,0.f); o.w = fmaxf(o.w,0.f); }
            *(float4*)(outL + (size_t)(j0 + 1) * MP + e0) = o;
        }
        if (j0 + 2 < N) {
            float s = su2 + (bias ? bias[j0 + 2] : 0.f);
            o.x = c20 + s; o.y = c21 + s; o.z = c22 + s; o.w = c23 + s;
            if (relu) { o.x = fmaxf(o.x,0.f); o.y = fmaxf(o.y,0.f); o.z = fmaxf(o.z,0.f); o.w = fmaxf(o.w,0.f); }
            *(float4*)(outL + (size_t)(j0 + 2) * MP + e0) = o;
        }
        if (j0 + 3 < N) {
            float s = su3 + (bias ? bias[j0 + 3] : 0.f);
            o.x = c30 + s; o.y = c31 + s; o.z = c32 + s; o.w = c33 + s;
            if (relu) { o.x = fmaxf(o.x,0.f); o.y = fmaxf(o.y,0.f); o.z = fmaxf(o.z,0.f); o.w = fmaxf(o.w,0.f); }
            *(float4*)(outL + (size_t)(j0 + 3) * MP + e0) = o;
        }
    }
}

// ---------------------------------------------------------------------------
// Direct-B fp32 GEMM (proven compile-safe, round 6). Single contiguous A in
// LDS; B straight from global (L1/L2-hot). N%4==0 && ldB%4==0. One internal
// barrier before stores (so outL may alias A).
// ---------------------------------------------------------------------------
__device__ void gemm_d(const float* A, int Ktot,
                       const float* Bg, int ldB, int N,
                       const float* bias, bool relu,
                       float* outL, int MP, int tid)
{
    const int EQ = MP >> 2;
    const int npairs = EQ * (N >> 2);
    const bool active = tid < npairs;
    const int e0 = (active ? (tid % EQ) : 0) * 4;
    const int j0 = (active ? (tid / EQ) : 0) * 4;

    float c00=0.f,c01=0.f,c02=0.f,c03=0.f;
    float c10=0.f,c11=0.f,c12=0.f,c13=0.f;
    float c20=0.f,c21=0.f,c22=0.f,c23=0.f;
    float c30=0.f,c31=0.f,c32=0.f,c33=0.f;

    if (active) {
        for (int k = 0; k < Ktot; ++k) {
            float4 a4 = *(const float4*)(A + (size_t)k * MP + e0);
            float4 b4 = *(const float4*)(Bg + (size_t)k * ldB + j0);
            c00 = fmaf(a4.x, b4.x, c00); c01 = fmaf(a4.y, b4.x, c01);
            c02 = fmaf(a4.z, b4.x, c02); c03 = fmaf(a4.w, b4.x, c03);
            c10 = fmaf(a4.x, b4.y, c10); c11 = fmaf(a4.y, b4.y, c11);
            c12 = fmaf(a4.z, b4.y, c12); c13 = fmaf(a4.w, b4.y, c13);
            c20 = fmaf(a4.x, b4.z, c20); c21 = fmaf(a4.y, b4.z, c21);
            c22 = fmaf(a4.z, b4.z, c22); c23 = fmaf(a4.w, b4.z, c23);
            c30 = fmaf(a4.x, b4.w, c30); c31 = fmaf(a4.y, b4.w, c31);
            c32 = fmaf(a4.z, b4.w, c32); c33 = fmaf(a4.w, b4.w, c33);
        }
    }
    __syncthreads();
    if (active) {
        float4 o;
        float s0 = bias ? bias[j0 + 0] : 0.f;
        o.x = c00 + s0; o.y = c01 + s0; o.z = c02 + s0; o.w = c03 + s0;
        if (relu) { o.x = fmaxf(o.x,0.f); o.y = fmaxf(o.y,0.f); o.z = fmaxf(o.z,0.f); o.w = fmaxf(o.w,0.f); }
        *(float4*)(outL + (size_t)(j0 + 0) * MP + e0) = o;
        float s1 = bias ? bias[j0 + 1] : 0.f;
        o.x = c10 + s1; o.y = c11 + s1; o.z = c12 + s1; o.w = c13 + s1;
        if (relu) { o.x = fmaxf(o.x,0.f); o.y = fmaxf(o.y,0.f); o.z = fmaxf(o.z,0.f); o.w = fmaxf(o.w,0.f); }
        *(float4*)(outL + (size_t)(j0 + 1) * MP + e0) = o;
        float s2 = bias ? bias[j0 + 2] : 0.f;
        o.x = c20 + s2; o.y = c21 + s2; o.z = c22 + s2; o.w = c23 + s2;
        if (relu) { o.x = fmaxf(o.x,0.f); o.y = fmaxf(o.y,0.f); o.z = fmaxf(o.z,0.f); o.w = fmaxf(o.w,0.f); }
        *(float4*)(outL + (size_t)(j0 + 2) * MP + e0) = o;
        float s3 = bias ? bias[j0 + 3] : 0.f;
        o.x = c30 + s3; o.y = c31 + s3; o.z = c32 + s3; o.w = c33 + s3;
        if (relu) { o.x = fmaxf(o.x,0.f); o.y = fmaxf(o.y,0.f); o.z = fmaxf(o.z,0.f); o.w = fmaxf(o.w,0.f); }
        *(float4*)(outL + (size_t)(j0 + 3) * MP + e0) = o;
    }
}

__device__ void vn_dev(const float* vh, int nch, int MP, int cs,
                       float* out, int ostr, int tid)
{
    for (int idx = tid; idx < nch * cs; idx += NT) {
        int h = idx / cs, e = idx - h * cs;
        float a = vh[h * MP + e], b = vh[h * MP + cs + e], c = vh[h * MP + 2 * cs + e];
        out[h * ostr + e] = sqrtf(fmaxf(a * a + b * b + c * c, 1e-8f));
    }
}

__device__ void gate_dev(float* vb, int nch, int MP, int cs, int tid)
{
    for (int idx = tid; idx < nch * cs; idx += NT) {
        int o = idx / cs, e = idx - o * cs;
        float* b = vb + o * MP + e;
        float a = b[0], b1 = b[cs], c = b[2 * cs];
        float n = sqrtf(fmaxf(a * a + b1 * b1 + c * c, 1e-8f));
        float g = 1.f / (1.f + expf(-n));
        b[0] = a * g; b[cs] = b1 * g; b[2 * cs] = c * g;
    }
}

// ---------------------------------------------------------------------------
// MFMA GEMM: M=32 edges, N=100 (7 n-tiles of 16, cols>=100 discarded),
// A bf16 LDS [32][Astr], B bf16 GLOBAL [112][Kpad] ([n][k], prep-transposed).
// bias may live in LDS (GEMM1 uses the per-block ubias).
// ---------------------------------------------------------------------------
__device__ void mfma_gemm(const short* Alds, int Astr, const short* Bg, int Kpad,
                          int ktiles, const float* bias,
                          short* outA, int outAstr, float* outS, int tid)
{
    const int w = tid >> 6, lane = tid & 63;
    const int q = lane >> 4, l16 = lane & 15;
    for (int t = w; t < 14; t += 4) {
        int mt = t & 1, nt = t >> 1;
        const short* ap = Alds + (mt * 16 + l16) * Astr + q * 8;
        const short* bp = Bg + (size_t)(nt * 16 + l16) * Kpad + q * 8;
        float4v acc = {0.f, 0.f, 0.f, 0.f};
        for (int kt = 0; kt < ktiles; ++kt) {
            short8 a = *(const short8*)(ap + kt * 32);
            short8 b = *(const short8*)(bp + kt * 32);
            acc = __builtin_amdgcn_mfma_f32_16x16x32_bf16(a, b, acc, 0, 0, 0);
        }
        int j = nt * 16 + l16;
        if (j < 100) {
            float bj = bias ? bias[j] : 0.f;
            int ebase = mt * 16 + q * 4;
            for (int r = 0; r < 4; ++r) {
                float v = acc[r] + bj;
                if (outA) { v = fmaxf(v, 0.f); outA[(ebase + r) * outAstr + j] = f2bf(v); }
                else      { outS[j * 33 + (ebase + r)] = v; }
            }
        }
    }
}

// ---------------------------------------------------------------------------
// prep: wt1 [112][192] (hM_s cols 0..131 = ws rows 100..231, vn cols 132..164
// = ws rows 232..264, zero pad 165..191 — hV_s contribution folded into the
// per-block ubias instead). wt2/wt3 [112][128]. wp1h = w1h padded to [33][36].
// ---------------------------------------------------------------------------
__global__ __launch_bounds__(NT) void prep_w(P28 p)
{
    int id = blockIdx.x * NT + threadIdx.x;
    int stride = gridDim.x * NT;
    for (int i = id; i < 112 * 192; i += stride) {
        int n = i / 192, k = i - n * 192;
        float v = 0.f;
        if (n < 100) {
            int row = -1;
            if (k < 132) row = 100 + k;
            else if (k < 165) row = 232 + (k - 132);
            if (row >= 0) v = p.w1s[(size_t)row * 100 + n];
        }
        p.wt1[i] = f2bf(v);
    }
    for (int i = id; i < 112 * 128; i += stride) {
        int n = i / 128, k = i - n * 128;
        p.wt2[i] = f2bf((n < 100 && k < 116) ? p.w2s[(size_t)k * 100 + n] : 0.f);
    }
    for (int i = id; i < 112 * 128; i += stride) {
        int n = i / 128, k = i - n * 128;
        p.wt3[i] = f2bf((n < 100 && k < 116) ? p.w3s[(size_t)k * 100 + n] : 0.f);
    }
    for (int i = id; i < 33 * 36; i += stride) {
        int k = i / 36, j = i - k * 36;
        p.wp1h[i] = (j < 33) ? p.w1h[(size_t)k * 33 + j] : 0.f;
    }
}

// ---------------------------------------------------------------------------
// Edge kernel v2: one block per node; 30 edges (+2 pad).
// LDS 39,840 B -> 4 blocks/CU (was 50,176 -> 3). ~19 barriers (was ~35).
//  - hV-scalar K-range of GEMM1 folded into ubias (rank-1, fp32 exact);
//    A1 shrinks to [32][192], GEMM1 ktiles 9 -> 6.
//  - All v-path gemms direct-B (gemm_d, no Bbuf); w1h prep-padded to [33][36].
//  - gate_dev merged into MFMA phases (disjoint LDS).
// ---------------------------------------------------------------------------
__global__ __launch_bounds__(NT) void edge_kernel(P28 p)
{
    __shared__ __align__(16) short A1s[32 * 192];     // 12.3 KB GEMM1 A; later A3 [32][136]
    __shared__ __align__(16) float bufY[3300];        // 13.2 KB vbuf -> A2 (bf16) -> S3 (fp32)
    __shared__ __align__(16) float vhb[36 * 96];      // 13.8 KB v-path fp32 ping-pong (36 rows: padded w1h out)
    __shared__ __align__(16) float ubias[100];        //  0.4 KB GEMM1 fused bias
    __shared__ float maskf[32];

    short* A3s = A1s;                 // 32*136 sh = 8.7 KB <= 32*192
    short* A2s = (short*)bufY;        // 32*136 sh = 8.7 KB <= bufY
    float* vbuf = bufY;               // 33*96 f
    float* S3   = bufY;               // 100*33 f

    const int node = blockIdx.x, tid = threadIdx.x;
    const float* hV = p.h_V + (size_t)node * 148;

    for (int i = tid; i < 32; i += NT)
        maskf[i] = (i < 30) ? (float)p.mask_attend[(size_t)node * 30 + i] : 0.f;
    // A1 cols 0..131: hM scalars bf16
    for (int idx = tid; idx < 32 * 132; idx += NT) {
        int e = idx / 132, k = idx - e * 132;
        float v = (e < 30) ? p.h_M[((size_t)node * 30 + e) * 183 + 51 + k] : 0.f;
        A1s[e * 192 + k] = f2bf(v);
    }
    // A1 cols 165..191: zero K pad
    for (int idx = tid; idx < 32 * 27; idx += NT) {
        int kk = idx >> 5, e = idx & 31;
        A1s[e * 192 + 165 + kk] = 0;
    }
    // vbuf fp32 vectors [i][c*32+e]
    for (int idx = tid; idx < 33 * 96; idx += NT) {
        int i = idx / 96, r = idx - i * 96, c = r >> 5, e = r & 31;
        float v = 0.f;
        if (i < 16) v = hV[c * 16 + i];
        else if (e < 30) v = p.h_M[((size_t)node * 30 + e) * 183 + c * 17 + (i - 16)];
        vbuf[idx] = v;
    }
    // ubias[j] = b1[j] + sum_i hVs[i] * w1s[i][j] (rank-1 hV-scalar term, fp32)
    for (int j = tid; j < 100; j += NT) {
        float s = p.b1[j];
        for (int i = 0; i < 100; ++i)
            s = fmaf(hV[48 + i], p.w1s[(size_t)i * 100 + j], s);
        ubias[j] = s;
    }
    __syncthreads();

    // ---- GVP1 v-path: vh1 = vbuf @ wp1h ([33][36] padded) ----
    gemm_d(vbuf, 33, p.wp1h, 36, 36, nullptr, false, vhb, 96, tid);
    __syncthreads();
    // vn1 -> A1 cols 132..164; zero A2 pad cols 116..127 (vbuf dead)
    for (int idx = tid; idx < 33 * 32; idx += NT) {
        int h = idx >> 5, e = idx & 31;
        float a = vhb[h * 96 + e], b = vhb[h * 96 + 32 + e], c = vhb[h * 96 + 64 + e];
        A1s[e * 192 + 132 + h] = f2bf(sqrtf(fmaxf(a * a + b * b + c * c, 1e-8f)));
    }
    for (int idx = tid; idx < 32 * 12; idx += NT) {
        int kk = idx >> 5, e = idx & 31;
        A2s[e * 136 + 116 + kk] = 0;
    }
    __syncthreads();
    // v1 = vh1 @ w1v (out aliases A rows 0..15; internal barrier)
    gemm_d(vhb, 33, p.w1v, 16, 16, nullptr, false, vhb, 96, tid);
    __syncthreads();
    // gate(v1) || GEMM1: s1 = relu(A1 @ wt1 + ubias) -> A2 (disjoint LDS)
    gate_dev(vhb, 16, 96, 32, tid);
    mfma_gemm(A1s, 192, p.wt1, 192, 6, ubias, A2s, 136, nullptr, tid);
    __syncthreads();

    // ---- GVP2 ----
    gemm_d(vhb, 16, p.w2h, 16, 16, nullptr, false, vhb + 16 * 96, 96, tid);
    __syncthreads();
    // vn2 -> A2 cols 100..115; zero A3 pad cols (A1 dead after GEMM1)
    for (int idx = tid; idx < 16 * 32; idx += NT) {
        int h = idx >> 5, e = idx & 31;
        float a = vhb[(16 + h) * 96 + e], b = vhb[(16 + h) * 96 + 32 + e], c = vhb[(16 + h) * 96 + 64 + e];
        A2s[e * 136 + 100 + h] = f2bf(sqrtf(fmaxf(a * a + b * b + c * c, 1e-8f)));
    }
    for (int idx = tid; idx < 32 * 12; idx += NT) {
        int kk = idx >> 5, e = idx & 31;
        A3s[e * 136 + 116 + kk] = 0;
    }
    __syncthreads();
    gemm_d(vhb + 16 * 96, 16, p.w2v, 16, 16, nullptr, false, vhb, 96, tid);
    __syncthreads();
    gate_dev(vhb, 16, 96, 32, tid);
    mfma_gemm(A2s, 136, p.wt2, 128, 4, p.b2, A3s, 136, nullptr, tid);
    __syncthreads();

    // ---- GVP3 (no gate) ----
    gemm_d(vhb, 16, p.w3h, 16, 16, nullptr, false, vhb + 16 * 96, 96, tid);
    __syncthreads();
    for (int idx = tid; idx < 16 * 32; idx += NT) {
        int h = idx >> 5, e = idx & 31;
        float a = vhb[(16 + h) * 96 + e], b = vhb[(16 + h) * 96 + 32 + e], c = vhb[(16 + h) * 96 + 64 + e];
        A3s[e * 136 + 100 + h] = f2bf(sqrtf(fmaxf(a * a + b * b + c * c, 1e-8f)));
    }
    __syncthreads();
    gemm_d(vhb + 16 * 96, 16, p.w3v, 16, 16, nullptr, false, vhb, 96, tid);
    __syncthreads();
    // GEMM3: s3 = A3 @ wt3 + b3 -> S3 fp32 [j][33] (A2 dead)
    mfma_gemm(A3s, 136, p.wt3, 128, 4, p.b3, nullptr, 0, S3, tid);
    __syncthreads();

    // ---- masked mean over 30 edges -> dh (staged in d_out) ----
    float* dhn = p.dh + (size_t)node * 148;
    for (int f = tid; f < 148; f += NT) {
        float s = 0.f;
        int e = f % 30;
        if (f < 48) {
            int c = f >> 4, o = f & 15;
            const float* src = vhb + o * 96 + c * 32;
            for (int t = 0; t < 30; ++t) { s += maskf[e] * src[e]; if (++e == 30) e = 0; }
        } else {
            const float* src = S3 + (size_t)(f - 48) * 33;
            for (int t = 0; t < 30; ++t) { s += maskf[e] * src[e]; if (++e == 30) e = 0; }
        }
        dhn[f] = s * (1.f / 30.f);
    }
}

// ---------------------------------------------------------------------------
// Node kernel: 16 nodes per block (round-0 verbatim — best measured config).
// ---------------------------------------------------------------------------
__global__ __launch_bounds__(NT) void node_kernel(P28 p)
{
    __shared__ __align__(16) float Bbuf[3200];
    __shared__ __align__(16) float S1n[132 * 16];
    __shared__ __align__(16) float A2n[400 * 16];
    __shared__ __align__(16) float s2n[100 * 16];
    __shared__ __align__(16) float hvv[16 * 48];
    __shared__ __align__(16) float vhA[32 * 48];
    __shared__ __align__(16) float vhB[32 * 48];
    __shared__ float mu[16], isd[16], vrm[16], mkv[16];

    const int nb = blockIdx.x * 16;
    const int tid = threadIdx.x;

    for (int idx = tid; idx < 1600; idx += NT) {
        int n = idx & 15, j = idx >> 4;
        size_t g = (size_t)(nb + n) * 148 + 48 + j;
        S1n[idx] = p.h_V[g] + p.dh[g];
    }
    for (int idx = tid; idx < 768; idx += NT) {
        int i = idx / 48, r = idx - i * 48, c = r >> 4, n = r & 15;
        size_t g = (size_t)(nb + n) * 148 + c * 16 + i;
        hvv[idx] = p.h_V[g] + p.dh[g];
    }
    for (int i = tid; i < 16; i += NT) mkv[i] = (float)p.mask_V[nb + i];
    __syncthreads();

    if (tid < 16) {
        int n = tid;
        float sm = 0.f;
        for (int j = 0; j < 100; ++j) sm += S1n[j * 16 + n];
        float m = sm * 0.01f, var = 0.f;
        for (int j = 0; j < 100; ++j) { float d = S1n[j * 16 + n] - m; var += d * d; }
        mu[n] = m; isd[n] = rsqrtf(var * 0.01f + 1e-3f);
        float vm = 0.f;
        for (int i = 0; i < 16; ++i) {
            float a = hvv[i * 48 + n], b = hvv[i * 48 + 16 + n], c = hvv[i * 48 + 32 + n];
            vm += fmaxf(a * a + b * b + c * c, 1e-8f);
        }
        vrm[n] = rsqrtf(vm * (1.f / 16.f));
    }
    __syncthreads();
    for (int idx = tid; idx < 1600; idx += NT) {
        int n = idx & 15, j = idx >> 4;
        S1n[idx] = (S1n[idx] - mu[n]) * isd[n] * p.g1[j] + p.be1[j];
    }
    for (int idx = tid; idx < 768; idx += NT) hvv[idx] *= vrm[idx & 15];
    __syncthreads();

    gemm(hvv, 16, nullptr, 16, nullptr, 0, p.d1h, 32, 32, nullptr, false, vhA, 48, Bbuf, 3200, tid);
    __syncthreads();
    vn_dev(vhA, 32, 48, 16, S1n + 100 * 16, 16, tid);
    __syncthreads();
    gemm(S1n, 132, nullptr, 132, nullptr, 0, p.d1s,       400, 200, p.db1,       true, A2n,            16, Bbuf, 3200, tid);
    gemm(S1n, 132, nullptr, 132, nullptr, 0, p.d1s + 200, 400, 200, p.db1 + 200, true, A2n + 200 * 16, 16, Bbuf, 3200, tid);
    gemm(vhA, 32, nullptr, 32, nullptr, 0, p.d1v, 32, 32, nullptr, false, vhB, 48, Bbuf, 3200, tid);
    __syncthreads();
    gate_dev(vhB, 32, 48, 16, tid);
    __syncthreads();

    gemm(vhB, 32, nullptr, 32, nullptr, 0, p.d2h, 32, 32, nullptr, false, vhA, 48, Bbuf, 3200, tid);
    __syncthreads();
    vn_dev(vhA, 32, 48, 16, S1n + 100 * 16, 16, tid);
    __syncthreads();
    gemm(A2n, 400, S1n + 100 * 16, 432, nullptr, 0, p.d2s, 100, 100, p.db2, false, s2n, 16, Bbuf, 3200, tid);
    gemm(vhA, 32, nullptr, 32, nullptr, 0, p.d2v, 16, 16, nullptr, false, vhB, 48, Bbuf, 3200, tid);
    __syncthreads();

    for (int idx = tid; idx < 1600; idx += NT) s2n[idx] += S1n[idx];
    for (int idx = tid; idx < 768; idx += NT) vhB[idx] += hvv[idx];
    __syncthreads();

    if (tid < 16) {
        int n = tid;
        float sm = 0.f;
        for (int j = 0; j < 100; ++j) sm += s2n[j * 16 + n];
        float m = sm * 0.01f, var = 0.f;
        for (int j = 0; j < 100; ++j) { float d = s2n[j * 16 + n] - m; var += d * d; }
        mu[n] = m; isd[n] = rsqrtf(var * 0.01f + 1e-3f);
        float vm = 0.f;
        for (int i = 0; i < 16; ++i) {
            float a = vhB[i * 48 + n], b = vhB[i * 48 + 16 + n], c = vhB[i * 48 + 32 + n];
            vm += fmaxf(a * a + b * b + c * c, 1e-8f);
        }
        vrm[n] = rsqrtf(vm * (1.f / 16.f));
    }
    __syncthreads();
    for (int idx = tid; idx < 1600; idx += NT) {
        int n = idx & 15, j = idx >> 4;
        s2n[idx] = (s2n[idx] - mu[n]) * isd[n] * p.g2[j] + p.be2[j];
    }
    for (int idx = tid; idx < 768; idx += NT) vhB[idx] *= vrm[idx & 15];
    __syncthreads();

    for (int idx = tid; idx < 16 * 148; idx += NT) {
        int n = idx / 148, f = idx - n * 148;
        float v;
        if (f < 48) { int c = f >> 4, o = f & 15; v = vhB[o * 48 + c * 16 + n]; }
        else        { v = s2n[(f - 48) * 16 + n]; }
        p.out[(size_t)(nb + n) * 148 + f] = mkv[n] * v;
    }
}

extern "C" void kernel_launch(void* const* d_in, const int* in_sizes, int n_in,
                              void* d_out, int out_size, void* d_ws, size_t ws_size,
                              hipStream_t stream)
{
    P28 p;
    p.h_V = (const float*)d_in[0];
    p.h_M = (const float*)d_in[1];
    p.mask_V = (const int*)d_in[2];
    p.mask_attend = (const int*)d_in[3];
    const float** w = (const float**)&p.w1h;
    for (int i = 0; i < 24; ++i) w[i] = (const float*)d_in[4 + i];
    p.out = (float*)d_out;
    p.dh  = (float*)d_out;              // stage dh in d_out; node kernel reads then overwrites
    p.wt1 = (short*)d_ws;               // 112*192 bf16
    p.wt2 = p.wt1 + 112 * 192;          // 112*128 bf16
    p.wt3 = p.wt2 + 112 * 128;          // 112*128 bf16
    p.wp1h = (float*)(p.wt3 + 112 * 128);   // 33*36 fp32 (offset 100,352 B, 16B-aligned)

    prep_w<<<dim3(64), dim3(NT), 0, stream>>>(p);
    edge_kernel<<<dim3(8192), dim3(NT), 0, stream>>>(p);
    node_kernel<<<dim3(512),  dim3(NT), 0, stream>>>(p);
}

// Round 9
// 781.954 us; speedup vs baseline: 1.0720x; 1.0528x over previous
//
#include <hip/hip_runtime.h>
#include <math.h>

#define NT 256

typedef __attribute__((ext_vector_type(8))) short short8;
typedef __attribute__((ext_vector_type(4))) float float4v;

struct P28 {
    const float *h_V, *h_M;
    const int *mask_V, *mask_attend;
    const float *w1h,*w1s,*b1,*w1v;
    const float *w2h,*w2s,*b2,*w2v;
    const float *w3h,*w3s,*b3,*w3v;
    const float *d1h,*d1s,*db1,*d1v;
    const float *d2h,*d2s,*db2,*d2v;
    const float *g1,*be1,*g2,*be2;
    float *out, *dh;
    short *wt1, *wt2, *wt3;   // bf16 [n][Kpad] weight layouts in d_ws
};

__device__ inline short f2bf(float f) {
    union { float f; unsigned u; } v; v.f = f;
    unsigned r = (v.u + 0x7FFFu + ((v.u >> 16) & 1u)) >> 16;   // RNE
    return (short)r;
}

// ---------------------------------------------------------------------------
// fp32 tiled GEMM (VALU) with LDS B staging — round-0 verbatim (proven fast:
// staged B beats per-thread direct-global B, round-8 A/B evidence).
// out[j*MP+e]; one thread = 4x4 tile. Requires (MP/4)*((N+3)/4) <= NT.
// Final __syncthreads() precedes stores, so outL may alias A0/A1.
// ---------------------------------------------------------------------------
__device__ void gemm(const float* A0, int split, const float* A1, int KA,
                     const float* uni, int uniK,
                     const float* Bg, int ldB, int N,
                     const float* bias, bool relu,
                     float* outL, int MP, float* Bbuf, int bbf, int tid)
{
    const bool vec = ((N & 3) == 0) && ((ldB & 3) == 0);
    const int Npad = vec ? N : ((N + 3) & ~3);
    const int EQ = MP >> 2;
    const int npairs = EQ * (Npad >> 2);
    const int Ktot = uniK + KA;
    int KC = bbf / Npad;
    if (KC > Ktot) KC = Ktot;

    const bool active = tid < npairs;
    const int e0 = (active ? (tid % EQ) : 0) * 4;
    const int j0 = (active ? (tid / EQ) : 0) * 4;

    float c00=0.f,c01=0.f,c02=0.f,c03=0.f;
    float c10=0.f,c11=0.f,c12=0.f,c13=0.f;
    float c20=0.f,c21=0.f,c22=0.f,c23=0.f;
    float c30=0.f,c31=0.f,c32=0.f,c33=0.f;
    float su0=0.f,su1=0.f,su2=0.f,su3=0.f;

    float4 r0, r1, r2, r3;
    r0.x=r0.y=r0.z=r0.w=0.f; r1=r0; r2=r0; r3=r0;

    if (vec) {
        int kc0 = (KC < Ktot) ? KC : Ktot;
        int nf4 = (kc0 * N) >> 2;
        int f4 = tid;
        if (f4 < nf4) { int f = f4*4; int k = f / N; r0 = *(const float4*)(Bg + (size_t)k*ldB + (f - k*N)); }
        f4 = tid + NT;
        if (f4 < nf4) { int f = f4*4; int k = f / N; r1 = *(const float4*)(Bg + (size_t)k*ldB + (f - k*N)); }
        f4 = tid + 2*NT;
        if (f4 < nf4) { int f = f4*4; int k = f / N; r2 = *(const float4*)(Bg + (size_t)k*ldB + (f - k*N)); }
        f4 = tid + 3*NT;
        if (f4 < nf4) { int f = f4*4; int k = f / N; r3 = *(const float4*)(Bg + (size_t)k*ldB + (f - k*N)); }
    }

    for (int k0 = 0; k0 < Ktot; k0 += KC) {
        int kc = Ktot - k0; if (kc > KC) kc = KC;
        __syncthreads();
        if (vec) {
            int nf4 = (kc * N) >> 2;
            float4* Bb4 = (float4*)Bbuf;
            if (tid        < nf4) Bb4[tid]        = r0;
            if (tid +   NT < nf4) Bb4[tid +   NT] = r1;
            if (tid + 2*NT < nf4) Bb4[tid + 2*NT] = r2;
            if (tid + 3*NT < nf4) Bb4[tid + 3*NT] = r3;
            int k0n = k0 + KC;
            if (k0n < Ktot) {
                int kcn = Ktot - k0n; if (kcn > KC) kcn = KC;
                int nf4n = (kcn * N) >> 2;
                const float* Bn = Bg + (size_t)k0n * ldB;
                int f4 = tid;
                if (f4 < nf4n) { int f = f4*4; int k = f / N; r0 = *(const float4*)(Bn + (size_t)k*ldB + (f - k*N)); }
                f4 = tid + NT;
                if (f4 < nf4n) { int f = f4*4; int k = f / N; r1 = *(const float4*)(Bn + (size_t)k*ldB + (f - k*N)); }
                f4 = tid + 2*NT;
                if (f4 < nf4n) { int f = f4*4; int k = f / N; r2 = *(const float4*)(Bn + (size_t)k*ldB + (f - k*N)); }
                f4 = tid + 3*NT;
                if (f4 < nf4n) { int f = f4*4; int k = f / N; r3 = *(const float4*)(Bn + (size_t)k*ldB + (f - k*N)); }
            }
        } else {
            for (int idx = tid; idx < kc * Npad; idx += NT) {
                int k = idx / Npad, j = idx - k * Npad;
                Bbuf[idx] = (j < N) ? Bg[(size_t)(k0 + k) * ldB + j] : 0.f;
            }
        }
        __syncthreads();
        if (active) {
            for (int k = 0; k < kc; ++k) {
                int kg = k0 + k;
                float4 b4 = *(const float4*)(Bbuf + k * Npad + j0);
                if (kg < uniK) {
                    float u = uni[kg];
                    su0 = fmaf(u, b4.x, su0); su1 = fmaf(u, b4.y, su1);
                    su2 = fmaf(u, b4.z, su2); su3 = fmaf(u, b4.w, su3);
                } else {
                    int ka = kg - uniK;
                    const float* arow = (ka < split) ? (A0 + (size_t)ka * MP + e0)
                                                     : (A1 + (size_t)(ka - split) * MP + e0);
                    float4 a4 = *(const float4*)arow;
                    c00 = fmaf(a4.x, b4.x, c00); c01 = fmaf(a4.y, b4.x, c01);
                    c02 = fmaf(a4.z, b4.x, c02); c03 = fmaf(a4.w, b4.x, c03);
                    c10 = fmaf(a4.x, b4.y, c10); c11 = fmaf(a4.y, b4.y, c11);
                    c12 = fmaf(a4.z, b4.y, c12); c13 = fmaf(a4.w, b4.y, c13);
                    c20 = fmaf(a4.x, b4.z, c20); c21 = fmaf(a4.y, b4.z, c21);
                    c22 = fmaf(a4.z, b4.z, c22); c23 = fmaf(a4.w, b4.z, c23);
                    c30 = fmaf(a4.x, b4.w, c30); c31 = fmaf(a4.y, b4.w, c31);
                    c32 = fmaf(a4.z, b4.w, c32); c33 = fmaf(a4.w, b4.w, c33);
                }
            }
        }
    }
    __syncthreads();
    if (active) {
        float4 o;
        if (j0 + 0 < N) {
            float s = su0 + (bias ? bias[j0 + 0] : 0.f);
            o.x = c00 + s; o.y = c01 + s; o.z = c02 + s; o.w = c03 + s;
            if (relu) { o.x = fmaxf(o.x,0.f); o.y = fmaxf(o.y,0.f); o.z = fmaxf(o.z,0.f); o.w = fmaxf(o.w,0.f); }
            *(float4*)(outL + (size_t)(j0 + 0) * MP + e0) = o;
        }
        if (j0 + 1 < N) {
            float s = su1 + (bias ? bias[j0 + 1] : 0.f);
            o.x = c10 + s; o.y = c11 + s; o.z = c12 + s; o.w = c13 + s;
            if (relu) { o.x = fmaxf(o.x,0.f); o.y = fmaxf(o.y,0.f); o.z = fmaxf(o.z,0.f); o.w = fmaxf(o.w,0.f); }
            *(float4*)(outL + (size_t)(j0 + 1) * MP + e0) = o;
        }
        if (j0 + 2 < N) {
            float s = su2 + (bias ? bias[j0 + 2] : 0.f);
            o.x = c20 + s; o.y = c21 + s; o.z = c22 + s; o.w = c23 + s;
            if (relu) { o.x = fmaxf(o.x,0.f); o.y = fmaxf(o.y,0.f); o.z = fmaxf(o.z,0.f); o.w = fmaxf(o.w,0.f); }
            *(float4*)(outL + (size_t)(j0 + 2) * MP + e0) = o;
        }
        if (j0 + 3 < N) {
            float s = su3 + (bias ? bias[j0 + 3] : 0.f);
            o.x = c30 + s; o.y = c31 + s; o.z = c32 + s; o.w = c33 + s;
            if (relu) { o.x = fmaxf(o.x,0.f); o.y = fmaxf(o.y,0.f); o.z = fmaxf(o.z,0.f); o.w = fmaxf(o.w,0.f); }
            *(float4*)(outL + (size_t)(j0 + 3) * MP + e0) = o;
        }
    }
}

__device__ void vn_dev(const float* vh, int nch, int MP, int cs,
                       float* out, int ostr, int tid)
{
    for (int idx = tid; idx < nch * cs; idx += NT) {
        int h = idx / cs, e = idx - h * cs;
        float a = vh[h * MP + e], b = vh[h * MP + cs + e], c = vh[h * MP + 2 * cs + e];
        out[h * ostr + e] = sqrtf(fmaxf(a * a + b * b + c * c, 1e-8f));
    }
}

__device__ void gate_dev(float* vb, int nch, int MP, int cs, int tid)
{
    for (int idx = tid; idx < nch * cs; idx += NT) {
        int o = idx / cs, e = idx - o * cs;
        float* b = vb + o * MP + e;
        float a = b[0], b1 = b[cs], c = b[2 * cs];
        float n = sqrtf(fmaxf(a * a + b1 * b1 + c * c, 1e-8f));
        float g = 1.f / (1.f + expf(-n));
        b[0] = a * g; b[cs] = b1 * g; b[2 * cs] = c * g;
    }
}

// ---------------------------------------------------------------------------
// MFMA GEMM: M=32 edges, N=100 (7 n-tiles of 16, cols>=100 discarded),
// A bf16 LDS [32][Astr], B bf16 GLOBAL [112][Kpad] ([n][k], prep-transposed).
// 14 tiles over 4 waves. Layouts (m89/m120):
//   a: A[m=lane&15][k=(lane>>4)*8+j]  b: B[k=(lane>>4)*8+j][n=lane&15]
//   D: row=(lane>>4)*4+r, col=lane&15.
// Epilogue: outA != null -> relu+bias, bf16 -> outA[e][j].
//           else -> masked edge-sum via LDS atomicAdd into Sred[j]
//                   (fused mean; no shfl -> ICE-safe).
// ---------------------------------------------------------------------------
__device__ void mfma_gemm(const short* Alds, int Astr, const short* Bg, int Kpad,
                          int ktiles, const float* bias,
                          short* outA, int outAstr,
                          float* Sred, const float* maskf, int tid)
{
    const int w = tid >> 6, lane = tid & 63;
    const int q = lane >> 4, l16 = lane & 15;
    for (int t = w; t < 14; t += 4) {
        int mt = t & 1, nt = t >> 1;
        const short* ap = Alds + (mt * 16 + l16) * Astr + q * 8;
        const short* bp = Bg + (size_t)(nt * 16 + l16) * Kpad + q * 8;
        float4v acc = {0.f, 0.f, 0.f, 0.f};
        for (int kt = 0; kt < ktiles; ++kt) {
            short8 a = *(const short8*)(ap + kt * 32);
            short8 b = *(const short8*)(bp + kt * 32);
            acc = __builtin_amdgcn_mfma_f32_16x16x32_bf16(a, b, acc, 0, 0, 0);
        }
        int j = nt * 16 + l16;
        if (j < 100) {
            float bj = bias ? bias[j] : 0.f;
            int ebase = mt * 16 + q * 4;
            if (outA) {
                for (int r = 0; r < 4; ++r) {
                    float v = fmaxf(acc[r] + bj, 0.f);
                    outA[(ebase + r) * outAstr + j] = f2bf(v);
                }
            } else {
                float part = 0.f;
                for (int r = 0; r < 4; ++r) part += maskf[ebase + r] * (acc[r] + bj);
                atomicAdd(&Sred[j], part);
            }
        }
    }
}

// ---------------------------------------------------------------------------
// prep: wt1 [112][192] (hM_s cols 0..131 = ws rows 100..231, vn cols 132..164
// = ws rows 232..264, zero pad — hV_s contribution folded into per-block
// ubias). wt2/wt3 [112][128]. (Layouts validated in round 8.)
// ---------------------------------------------------------------------------
__global__ __launch_bounds__(NT) void prep_w(P28 p)
{
    int id = blockIdx.x * NT + threadIdx.x;
    int stride = gridDim.x * NT;
    for (int i = id; i < 112 * 192; i += stride) {
        int n = i / 192, k = i - n * 192;
        float v = 0.f;
        if (n < 100) {
            int row = -1;
            if (k < 132) row = 100 + k;
            else if (k < 165) row = 232 + (k - 132);
            if (row >= 0) v = p.w1s[(size_t)row * 100 + n];
        }
        p.wt1[i] = f2bf(v);
    }
    for (int i = id; i < 112 * 128; i += stride) {
        int n = i / 128, k = i - n * 128;
        p.wt2[i] = f2bf((n < 100 && k < 116) ? p.w2s[(size_t)k * 100 + n] : 0.f);
    }
    for (int i = id; i < 112 * 128; i += stride) {
        int n = i / 128, k = i - n * 128;
        p.wt3[i] = f2bf((n < 100 && k < 116) ? p.w3s[(size_t)k * 100 + n] : 0.f);
    }
}

// ---------------------------------------------------------------------------
// Edge kernel v3: one block per node; 30 edges (+2 pad).
// LDS 39,904 B (was 50,176). Bbuf-staged v-path gemms (round-0, proven).
//  - ubias rank-1 fold (validated r8): A1s [32][stride 200] (400 B row ->
//    2-way LDS banks, free), GEMM1 ktiles 6, no hV staging.
//  - GVP1-h in place (vh1 overwrites vbuf) - deletes bufY.
//  - GEMM3 epilogue fuses masked mean via LDS atomicAdd -> Sred (no S3).
// ---------------------------------------------------------------------------
__global__ __launch_bounds__(NT) void edge_kernel(P28 p)
{
    __shared__ __align__(16) short A1s[32 * 200];     // 12,800 B; later A3 [32][136]
    __shared__ __align__(16) float vhb[33 * 96];      // 12,672 B: vbuf -> vh (in place) -> v ping-pong
    __shared__ __align__(16) short A2s[32 * 136];     //  8,704 B
    __shared__ __align__(16) float Bbuf[1200];        //  4,800 B (v-path weight staging)
    __shared__ float Sred[100];                       //    400 B fused s-mean accumulator
    __shared__ float ubias[100];                      //    400 B GEMM1 fused bias
    __shared__ float maskf[32];                       //    128 B

    short* A3s = A1s;   // [32][136] = 8,704 B <= A1s

    const int node = blockIdx.x, tid = threadIdx.x;
    const float* hV = p.h_V + (size_t)node * 148;

    for (int i = tid; i < 32; i += NT)
        maskf[i] = (i < 30) ? (float)p.mask_attend[(size_t)node * 30 + i] : 0.f;
    for (int i = tid; i < 100; i += NT) Sred[i] = 0.f;
    // A1 cols 0..131: hM scalars bf16 (coalesced over k within an e-row)
    for (int idx = tid; idx < 32 * 132; idx += NT) {
        int e = idx / 132, k = idx - e * 132;
        float v = (e < 30) ? p.h_M[((size_t)node * 30 + e) * 183 + 51 + k] : 0.f;
        A1s[e * 200 + k] = f2bf(v);
    }
    // A1 cols 165..191: zero K pad (cols 192..199 never read)
    for (int idx = tid; idx < 32 * 27; idx += NT) {
        int kk = idx >> 5, e = idx & 31;
        A1s[e * 200 + 165 + kk] = 0;
    }
    // A2 pad cols 116..127: zero (A2s is its own buffer now)
    for (int idx = tid; idx < 32 * 12; idx += NT) {
        int kk = idx >> 5, e = idx & 31;
        A2s[e * 136 + 116 + kk] = 0;
    }
    // vbuf fp32 vectors [i][c*32+e]: rows 0..15 hV (replicated), 16..32 hM
    for (int idx = tid; idx < 33 * 96; idx += NT) {
        int i = idx / 96, r = idx - i * 96, c = r >> 5, e = r & 31;
        float v = 0.f;
        if (i < 16) v = hV[c * 16 + i];
        else if (e < 30) v = p.h_M[((size_t)node * 30 + e) * 183 + c * 17 + (i - 16)];
        vhb[idx] = v;
    }
    // ubias[j] = b1[j] + sum_i hVs[i] * w1s[i][j] (rank-1 hV-scalar fold, fp32)
    for (int j = tid; j < 100; j += NT) {
        float s = p.b1[j];
        for (int i = 0; i < 100; ++i)
            s = fmaf(hV[48 + i], p.w1s[(size_t)i * 100 + j], s);
        ubias[j] = s;
    }
    __syncthreads();

    // ---- GVP1 v-path: vh1 = vbuf @ w1h (IN PLACE; gemm's internal barrier
    // precedes its stores, so reading A == writing out is safe) ----
    gemm(vhb, 33, nullptr, 33, nullptr, 0, p.w1h, 33, 33, nullptr, false, vhb, 96, Bbuf, 1200, tid);
    __syncthreads();
    // vn1 -> A1 cols 132..164
    for (int idx = tid; idx < 33 * 32; idx += NT) {
        int h = idx >> 5, e = idx & 31;
        float a = vhb[h * 96 + e], b = vhb[h * 96 + 32 + e], c = vhb[h * 96 + 64 + e];
        A1s[e * 200 + 132 + h] = f2bf(sqrtf(fmaxf(a * a + b * b + c * c, 1e-8f)));
    }
    __syncthreads();
    // v1 = vh1 @ w1v (in place rows 0..15)
    gemm(vhb, 33, nullptr, 33, nullptr, 0, p.w1v, 16, 16, nullptr, false, vhb, 96, Bbuf, 1200, tid);
    __syncthreads();
    // gate(v1) || GEMM1: s1 = relu(A1 @ wt1 + ubias) -> A2 (disjoint LDS)
    gate_dev(vhb, 16, 96, 32, tid);
    mfma_gemm(A1s, 200, p.wt1, 192, 6, ubias, A2s, 136, nullptr, nullptr, tid);
    __syncthreads();

    // ---- GVP2 ----
    gemm(vhb, 16, nullptr, 16, nullptr, 0, p.w2h, 16, 16, nullptr, false, vhb + 16 * 96, 96, Bbuf, 1200, tid);
    __syncthreads();
    // vn2 -> A2 cols 100..115; zero A3 pad cols (A1 dead after GEMM1)
    for (int idx = tid; idx < 16 * 32; idx += NT) {
        int h = idx >> 5, e = idx & 31;
        float a = vhb[(16 + h) * 96 + e], b = vhb[(16 + h) * 96 + 32 + e], c = vhb[(16 + h) * 96 + 64 + e];
        A2s[e * 136 + 100 + h] = f2bf(sqrtf(fmaxf(a * a + b * b + c * c, 1e-8f)));
    }
    for (int idx = tid; idx < 32 * 12; idx += NT) {
        int kk = idx >> 5, e = idx & 31;
        A3s[e * 136 + 116 + kk] = 0;
    }
    __syncthreads();
    gemm(vhb + 16 * 96, 16, nullptr, 16, nullptr, 0, p.w2v, 16, 16, nullptr, false, vhb, 96, Bbuf, 1200, tid);
    __syncthreads();
    // gate(v2) || GEMM2: s2 = relu(A2 @ wt2 + b2) -> A3
    gate_dev(vhb, 16, 96, 32, tid);
    mfma_gemm(A2s, 136, p.wt2, 128, 4, p.b2, A3s, 136, nullptr, nullptr, tid);
    __syncthreads();

    // ---- GVP3 (no gate) ----
    gemm(vhb, 16, nullptr, 16, nullptr, 0, p.w3h, 16, 16, nullptr, false, vhb + 16 * 96, 96, Bbuf, 1200, tid);
    __syncthreads();
    for (int idx = tid; idx < 16 * 32; idx += NT) {     // vn3 -> A3 cols 100..115
        int h = idx >> 5, e = idx & 31;
        float a = vhb[(16 + h) * 96 + e], b = vhb[(16 + h) * 96 + 32 + e], c = vhb[(16 + h) * 96 + 64 + e];
        A3s[e * 136 + 100 + h] = f2bf(sqrtf(fmaxf(a * a + b * b + c * c, 1e-8f)));
    }
    __syncthreads();
    gemm(vhb + 16 * 96, 16, nullptr, 16, nullptr, 0, p.w3v, 16, 16, nullptr, false, vhb, 96, Bbuf, 1200, tid);
    __syncthreads();
    // GEMM3: s3 = A3 @ wt3 + b3, fused masked edge-sum -> Sred (atomicAdd)
    mfma_gemm(A3s, 136, p.wt3, 128, 4, p.b3, nullptr, 0, Sred, maskf, tid);
    __syncthreads();

    // ---- dh: vector part (masked mean over vhb), scalar part from Sred ----
    float* dhn = p.dh + (size_t)node * 148;
    for (int f = tid; f < 148; f += NT) {
        float s;
        if (f < 48) {
            int c = f >> 4, o = f & 15;
            const float* src = vhb + o * 96 + c * 32;
            float acc = 0.f;
            int e = f % 30;
            for (int t = 0; t < 30; ++t) { acc += maskf[e] * src[e]; if (++e == 30) e = 0; }
            s = acc;
        } else {
            s = Sred[f - 48];
        }
        dhn[f] = s * (1.f / 30.f);
    }
}

// ---------------------------------------------------------------------------
// Node kernel: 16 nodes per block (round-0 verbatim — best measured config).
// ---------------------------------------------------------------------------
__global__ __launch_bounds__(NT) void node_kernel(P28 p)
{
    __shared__ __align__(16) float Bbuf[3200];
    __shared__ __align__(16) float S1n[132 * 16];
    __shared__ __align__(16) float A2n[400 * 16];
    __shared__ __align__(16) float s2n[100 * 16];
    __shared__ __align__(16) float hvv[16 * 48];
    __shared__ __align__(16) float vhA[32 * 48];
    __shared__ __align__(16) float vhB[32 * 48];
    __shared__ float mu[16], isd[16], vrm[16], mkv[16];

    const int nb = blockIdx.x * 16;
    const int tid = threadIdx.x;

    for (int idx = tid; idx < 1600; idx += NT) {
        int n = idx & 15, j = idx >> 4;
        size_t g = (size_t)(nb + n) * 148 + 48 + j;
        S1n[idx] = p.h_V[g] + p.dh[g];
    }
    for (int idx = tid; idx < 768; idx += NT) {
        int i = idx / 48, r = idx - i * 48, c = r >> 4, n = r & 15;
        size_t g = (size_t)(nb + n) * 148 + c * 16 + i;
        hvv[idx] = p.h_V[g] + p.dh[g];
    }
    for (int i = tid; i < 16; i += NT) mkv[i] = (float)p.mask_V[nb + i];
    __syncthreads();

    if (tid < 16) {
        int n = tid;
        float sm = 0.f;
        for (int j = 0; j < 100; ++j) sm += S1n[j * 16 + n];
        float m = sm * 0.01f, var = 0.f;
        for (int j = 0; j < 100; ++j) { float d = S1n[j * 16 + n] - m; var += d * d; }
        mu[n] = m; isd[n] = rsqrtf(var * 0.01f + 1e-3f);
        float vm = 0.f;
        for (int i = 0; i < 16; ++i) {
            float a = hvv[i * 48 + n], b = hvv[i * 48 + 16 + n], c = hvv[i * 48 + 32 + n];
            vm += fmaxf(a * a + b * b + c * c, 1e-8f);
        }
        vrm[n] = rsqrtf(vm * (1.f / 16.f));
    }
    __syncthreads();
    for (int idx = tid; idx < 1600; idx += NT) {
        int n = idx & 15, j = idx >> 4;
        S1n[idx] = (S1n[idx] - mu[n]) * isd[n] * p.g1[j] + p.be1[j];
    }
    for (int idx = tid; idx < 768; idx += NT) hvv[idx] *= vrm[idx & 15];
    __syncthreads();

    gemm(hvv, 16, nullptr, 16, nullptr, 0, p.d1h, 32, 32, nullptr, false, vhA, 48, Bbuf, 3200, tid);
    __syncthreads();
    vn_dev(vhA, 32, 48, 16, S1n + 100 * 16, 16, tid);
    __syncthreads();
    gemm(S1n, 132, nullptr, 132, nullptr, 0, p.d1s,       400, 200, p.db1,       true, A2n,            16, Bbuf, 3200, tid);
    gemm(S1n, 132, nullptr, 132, nullptr, 0, p.d1s + 200, 400, 200, p.db1 + 200, true, A2n + 200 * 16, 16, Bbuf, 3200, tid);
    gemm(vhA, 32, nullptr, 32, nullptr, 0, p.d1v, 32, 32, nullptr, false, vhB, 48, Bbuf, 3200, tid);
    __syncthreads();
    gate_dev(vhB, 32, 48, 16, tid);
    __syncthreads();

    gemm(vhB, 32, nullptr, 32, nullptr, 0, p.d2h, 32, 32, nullptr, false, vhA, 48, Bbuf, 3200, tid);
    __syncthreads();
    vn_dev(vhA, 32, 48, 16, S1n + 100 * 16, 16, tid);
    __syncthreads();
    gemm(A2n, 400, S1n + 100 * 16, 432, nullptr, 0, p.d2s, 100, 100, p.db2, false, s2n, 16, Bbuf, 3200, tid);
    gemm(vhA, 32, nullptr, 32, nullptr, 0, p.d2v, 16, 16, nullptr, false, vhB, 48, Bbuf, 3200, tid);
    __syncthreads();

    for (int idx = tid; idx < 1600; idx += NT) s2n[idx] += S1n[idx];
    for (int idx = tid; idx < 768; idx += NT) vhB[idx] += hvv[idx];
    __syncthreads();

    if (tid < 16) {
        int n = tid;
        float sm = 0.f;
        for (int j = 0; j < 100; ++j) sm += s2n[j * 16 + n];
        float m = sm * 0.01f, var = 0.f;
        for (int j = 0; j < 100; ++j) { float d = s2n[j * 16 + n] - m; var += d * d; }
        mu[n] = m; isd[n] = rsqrtf(var * 0.01f + 1e-3f);
        float vm = 0.f;
        for (int i = 0; i < 16; ++i) {
            float a = vhB[i * 48 + n], b = vhB[i * 48 + 16 + n], c = vhB[i * 48 + 32 + n];
            vm += fmaxf(a * a + b * b + c * c, 1e-8f);
        }
        vrm[n] = rsqrtf(vm * (1.f / 16.f));
    }
    __syncthreads();
    for (int idx = tid; idx < 1600; idx += NT) {
        int n = idx & 15, j = idx >> 4;
        s2n[idx] = (s2n[idx] - mu[n]) * isd[n] * p.g2[j] + p.be2[j];
    }
    for (int idx = tid; idx < 768; idx += NT) vhB[idx] *= vrm[idx & 15];
    __syncthreads();

    for (int idx = tid; idx < 16 * 148; idx += NT) {
        int n = idx / 148, f = idx - n * 148;
        float v;
        if (f < 48) { int c = f >> 4, o = f & 15; v = vhB[o * 48 + c * 16 + n]; }
        else        { v = s2n[(f - 48) * 16 + n]; }
        p.out[(size_t)(nb + n) * 148 + f] = mkv[n] * v;
    }
}

extern "C" void kernel_launch(void* const* d_in, const int* in_sizes, int n_in,
                              void* d_out, int out_size, void* d_ws, size_t ws_size,
                              hipStream_t stream)
{
    P28 p;
    p.h_V = (const float*)d_in[0];
    p.h_M = (const float*)d_in[1];
    p.mask_V = (const int*)d_in[2];
    p.mask_attend = (const int*)d_in[3];
    const float** w = (const float**)&p.w1h;
    for (int i = 0; i < 24; ++i) w[i] = (const float*)d_in[4 + i];
    p.out = (float*)d_out;
    p.dh  = (float*)d_out;              // stage dh in d_out; node kernel reads then overwrites
    p.wt1 = (short*)d_ws;               // 112*192 bf16
    p.wt2 = p.wt1 + 112 * 192;          // 112*128 bf16
    p.wt3 = p.wt2 + 112 * 128;          // 112*128 bf16

    prep_w<<<dim3(64), dim3(NT), 0, stream>>>(p);
    edge_kernel<<<dim3(8192), dim3(NT), 0, stream>>>(p);
    node_kernel<<<dim3(512),  dim3(NT), 0, stream>>>(p);
}

// Round 10
// 770.300 us; speedup vs baseline: 1.0882x; 1.0151x over previous
//
#include <hip/hip_runtime.h>
#include <math.h>

#define NT 256

typedef __attribute__((ext_vector_type(8))) short short8;
typedef __attribute__((ext_vector_type(4))) float float4v;

struct P28 {
    const float *h_V, *h_M;
    const int *mask_V, *mask_attend;
    const float *w1h,*w1s,*b1,*w1v;
    const float *w2h,*w2s,*b2,*w2v;
    const float *w3h,*w3s,*b3,*w3v;
    const float *d1h,*d1s,*db1,*d1v;
    const float *d2h,*d2s,*db2,*d2v;
    const float *g1,*be1,*g2,*be2;
    float *out, *dh;
    short *wt1, *wt2, *wt3;   // bf16 [n][Kpad] weight layouts in d_ws
};

__device__ inline short f2bf(float f) {
    union { float f; unsigned u; } v; v.f = f;
    unsigned r = (v.u + 0x7FFFu + ((v.u >> 16) & 1u)) >> 16;   // RNE
    return (short)r;
}

// ---------------------------------------------------------------------------
// fp32 tiled GEMM (VALU) with LDS B staging — NODE KERNEL (round-0 verbatim).
// ---------------------------------------------------------------------------
__device__ void gemm(const float* A0, int split, const float* A1, int KA,
                     const float* uni, int uniK,
                     const float* Bg, int ldB, int N,
                     const float* bias, bool relu,
                     float* outL, int MP, float* Bbuf, int bbf, int tid)
{
    const bool vec = ((N & 3) == 0) && ((ldB & 3) == 0);
    const int Npad = vec ? N : ((N + 3) & ~3);
    const int EQ = MP >> 2;
    const int npairs = EQ * (Npad >> 2);
    const int Ktot = uniK + KA;
    int KC = bbf / Npad;
    if (KC > Ktot) KC = Ktot;

    const bool active = tid < npairs;
    const int e0 = (active ? (tid % EQ) : 0) * 4;
    const int j0 = (active ? (tid / EQ) : 0) * 4;

    float c00=0.f,c01=0.f,c02=0.f,c03=0.f;
    float c10=0.f,c11=0.f,c12=0.f,c13=0.f;
    float c20=0.f,c21=0.f,c22=0.f,c23=0.f;
    float c30=0.f,c31=0.f,c32=0.f,c33=0.f;
    float su0=0.f,su1=0.f,su2=0.f,su3=0.f;

    float4 r0, r1, r2, r3;
    r0.x=r0.y=r0.z=r0.w=0.f; r1=r0; r2=r0; r3=r0;

    if (vec) {
        int kc0 = (KC < Ktot) ? KC : Ktot;
        int nf4 = (kc0 * N) >> 2;
        int f4 = tid;
        if (f4 < nf4) { int f = f4*4; int k = f / N; r0 = *(const float4*)(Bg + (size_t)k*ldB + (f - k*N)); }
        f4 = tid + NT;
        if (f4 < nf4) { int f = f4*4; int k = f / N; r1 = *(const float4*)(Bg + (size_t)k*ldB + (f - k*N)); }
        f4 = tid + 2*NT;
        if (f4 < nf4) { int f = f4*4; int k = f / N; r2 = *(const float4*)(Bg + (size_t)k*ldB + (f - k*N)); }
        f4 = tid + 3*NT;
        if (f4 < nf4) { int f = f4*4; int k = f / N; r3 = *(const float4*)(Bg + (size_t)k*ldB + (f - k*N)); }
    }

    for (int k0 = 0; k0 < Ktot; k0 += KC) {
        int kc = Ktot - k0; if (kc > KC) kc = KC;
        __syncthreads();
        if (vec) {
            int nf4 = (kc * N) >> 2;
            float4* Bb4 = (float4*)Bbuf;
            if (tid        < nf4) Bb4[tid]        = r0;
            if (tid +   NT < nf4) Bb4[tid +   NT] = r1;
            if (tid + 2*NT < nf4) Bb4[tid + 2*NT] = r2;
            if (tid + 3*NT < nf4) Bb4[tid + 3*NT] = r3;
            int k0n = k0 + KC;
            if (k0n < Ktot) {
                int kcn = Ktot - k0n; if (kcn > KC) kcn = KC;
                int nf4n = (kcn * N) >> 2;
                const float* Bn = Bg + (size_t)k0n * ldB;
                int f4 = tid;
                if (f4 < nf4n) { int f = f4*4; int k = f / N; r0 = *(const float4*)(Bn + (size_t)k*ldB + (f - k*N)); }
                f4 = tid + NT;
                if (f4 < nf4n) { int f = f4*4; int k = f / N; r1 = *(const float4*)(Bn + (size_t)k*ldB + (f - k*N)); }
                f4 = tid + 2*NT;
                if (f4 < nf4n) { int f = f4*4; int k = f / N; r2 = *(const float4*)(Bn + (size_t)k*ldB + (f - k*N)); }
                f4 = tid + 3*NT;
                if (f4 < nf4n) { int f = f4*4; int k = f / N; r3 = *(const float4*)(Bn + (size_t)k*ldB + (f - k*N)); }
            }
        } else {
            for (int idx = tid; idx < kc * Npad; idx += NT) {
                int k = idx / Npad, j = idx - k * Npad;
                Bbuf[idx] = (j < N) ? Bg[(size_t)(k0 + k) * ldB + j] : 0.f;
            }
        }
        __syncthreads();
        if (active) {
            for (int k = 0; k < kc; ++k) {
                int kg = k0 + k;
                float4 b4 = *(const float4*)(Bbuf + k * Npad + j0);
                if (kg < uniK) {
                    float u = uni[kg];
                    su0 = fmaf(u, b4.x, su0); su1 = fmaf(u, b4.y, su1);
                    su2 = fmaf(u, b4.z, su2); su3 = fmaf(u, b4.w, su3);
                } else {
                    int ka = kg - uniK;
                    const float* arow = (ka < split) ? (A0 + (size_t)ka * MP + e0)
                                                     : (A1 + (size_t)(ka - split) * MP + e0);
                    float4 a4 = *(const float4*)arow;
                    c00 = fmaf(a4.x, b4.x, c00); c01 = fmaf(a4.y, b4.x, c01);
                    c02 = fmaf(a4.z, b4.x, c02); c03 = fmaf(a4.w, b4.x, c03);
                    c10 = fmaf(a4.x, b4.y, c10); c11 = fmaf(a4.y, b4.y, c11);
                    c12 = fmaf(a4.z, b4.y, c12); c13 = fmaf(a4.w, b4.y, c13);
                    c20 = fmaf(a4.x, b4.z, c20); c21 = fmaf(a4.y, b4.z, c21);
                    c22 = fmaf(a4.z, b4.z, c22); c23 = fmaf(a4.w, b4.z, c23);
                    c30 = fmaf(a4.x, b4.w, c30); c31 = fmaf(a4.y, b4.w, c31);
                    c32 = fmaf(a4.z, b4.w, c32); c33 = fmaf(a4.w, b4.w, c33);
                }
            }
        }
    }
    __syncthreads();
    if (active) {
        float4 o;
        if (j0 + 0 < N) {
            float s = su0 + (bias ? bias[j0 + 0] : 0.f);
            o.x = c00 + s; o.y = c01 + s; o.z = c02 + s; o.w = c03 + s;
            if (relu) { o.x = fmaxf(o.x,0.f); o.y = fmaxf(o.y,0.f); o.z = fmaxf(o.z,0.f); o.w = fmaxf(o.w,0.f); }
            *(float4*)(outL + (size_t)(j0 + 0) * MP + e0) = o;
        }
        if (j0 + 1 < N) {
            float s = su1 + (bias ? bias[j0 + 1] : 0.f);
            o.x = c10 + s; o.y = c11 + s; o.z = c12 + s; o.w = c13 + s;
            if (relu) { o.x = fmaxf(o.x,0.f); o.y = fmaxf(o.y,0.f); o.z = fmaxf(o.z,0.f); o.w = fmaxf(o.w,0.f); }
            *(float4*)(outL + (size_t)(j0 + 1) * MP + e0) = o;
        }
        if (j0 + 2 < N) {
            float s = su2 + (bias ? bias[j0 + 2] : 0.f);
            o.x = c20 + s; o.y = c21 + s; o.z = c22 + s; o.w = c23 + s;
            if (relu) { o.x = fmaxf(o.x,0.f); o.y = fmaxf(o.y,0.f); o.z = fmaxf(o.z,0.f); o.w = fmaxf(o.w,0.f); }
            *(float4*)(outL + (size_t)(j0 + 2) * MP + e0) = o;
        }
        if (j0 + 3 < N) {
            float s = su3 + (bias ? bias[j0 + 3] : 0.f);
            o.x = c30 + s; o.y = c31 + s; o.z = c32 + s; o.w = c33 + s;
            if (relu) { o.x = fmaxf(o.x,0.f); o.y = fmaxf(o.y,0.f); o.z = fmaxf(o.z,0.f); o.w = fmaxf(o.w,0.f); }
            *(float4*)(outL + (size_t)(j0 + 3) * MP + e0) = o;
        }
    }
}

// ---------------------------------------------------------------------------
// LDS-cached-B fp32 GEMM — EDGE v-path. B already resident in LDS (persistent
// weight cache), so a call is: compute -> sync -> store. No global traffic,
// no staging phases. Requires N%4==0, ldB%4==0; stores guarded by Nst.
// outL may alias A (internal barrier precedes stores).
// Same code shape as gemm_d (compile-proven round 6).
// ---------------------------------------------------------------------------
__device__ void gemm_c(const float* A, int Ktot,
                       const float* Bl, int ldB, int N, int Nst,
                       float* outL, int MP, int tid)
{
    const int EQ = MP >> 2;
    const int npairs = EQ * (N >> 2);
    const bool active = tid < npairs;
    const int e0 = (active ? (tid % EQ) : 0) * 4;
    const int j0 = (active ? (tid / EQ) : 0) * 4;

    float c00=0.f,c01=0.f,c02=0.f,c03=0.f;
    float c10=0.f,c11=0.f,c12=0.f,c13=0.f;
    float c20=0.f,c21=0.f,c22=0.f,c23=0.f;
    float c30=0.f,c31=0.f,c32=0.f,c33=0.f;

    if (active) {
        for (int k = 0; k < Ktot; ++k) {
            float4 a4 = *(const float4*)(A + (size_t)k * MP + e0);
            float4 b4 = *(const float4*)(Bl + (size_t)k * ldB + j0);
            c00 = fmaf(a4.x, b4.x, c00); c01 = fmaf(a4.y, b4.x, c01);
            c02 = fmaf(a4.z, b4.x, c02); c03 = fmaf(a4.w, b4.x, c03);
            c10 = fmaf(a4.x, b4.y, c10); c11 = fmaf(a4.y, b4.y, c11);
            c12 = fmaf(a4.z, b4.y, c12); c13 = fmaf(a4.w, b4.y, c13);
            c20 = fmaf(a4.x, b4.z, c20); c21 = fmaf(a4.y, b4.z, c21);
            c22 = fmaf(a4.z, b4.z, c22); c23 = fmaf(a4.w, b4.z, c23);
            c30 = fmaf(a4.x, b4.w, c30); c31 = fmaf(a4.y, b4.w, c31);
            c32 = fmaf(a4.z, b4.w, c32); c33 = fmaf(a4.w, b4.w, c33);
        }
    }
    __syncthreads();
    if (active) {
        float4 o;
        if (j0 + 0 < Nst) {
            o.x = c00; o.y = c01; o.z = c02; o.w = c03;
            *(float4*)(outL + (size_t)(j0 + 0) * MP + e0) = o;
        }
        if (j0 + 1 < Nst) {
            o.x = c10; o.y = c11; o.z = c12; o.w = c13;
            *(float4*)(outL + (size_t)(j0 + 1) * MP + e0) = o;
        }
        if (j0 + 2 < Nst) {
            o.x = c20; o.y = c21; o.z = c22; o.w = c23;
            *(float4*)(outL + (size_t)(j0 + 2) * MP + e0) = o;
        }
        if (j0 + 3 < Nst) {
            o.x = c30; o.y = c31; o.z = c32; o.w = c33;
            *(float4*)(outL + (size_t)(j0 + 3) * MP + e0) = o;
        }
    }
}

__device__ void vn_dev(const float* vh, int nch, int MP, int cs,
                       float* out, int ostr, int tid)
{
    for (int idx = tid; idx < nch * cs; idx += NT) {
        int h = idx / cs, e = idx - h * cs;
        float a = vh[h * MP + e], b = vh[h * MP + cs + e], c = vh[h * MP + 2 * cs + e];
        out[h * ostr + e] = sqrtf(fmaxf(a * a + b * b + c * c, 1e-8f));
    }
}

__device__ void gate_dev(float* vb, int nch, int MP, int cs, int tid)
{
    for (int idx = tid; idx < nch * cs; idx += NT) {
        int o = idx / cs, e = idx - o * cs;
        float* b = vb + o * MP + e;
        float a = b[0], b1 = b[cs], c = b[2 * cs];
        float n = sqrtf(fmaxf(a * a + b1 * b1 + c * c, 1e-8f));
        float g = 1.f / (1.f + expf(-n));
        b[0] = a * g; b[cs] = b1 * g; b[2 * cs] = c * g;
    }
}

// ---------------------------------------------------------------------------
// MFMA GEMM: M=32 edges, N=100 (7 n-tiles of 16). A bf16 LDS [32][Astr],
// B bf16 GLOBAL [112][Kpad]. Epilogue: outA -> relu+bias bf16; else masked
// edge-sum via LDS atomicAdd into Sred (fused mean). (round-9 verbatim)
// ---------------------------------------------------------------------------
__device__ void mfma_gemm(const short* Alds, int Astr, const short* Bg, int Kpad,
                          int ktiles, const float* bias,
                          short* outA, int outAstr,
                          float* Sred, const float* maskf, int tid)
{
    const int w = tid >> 6, lane = tid & 63;
    const int q = lane >> 4, l16 = lane & 15;
    for (int t = w; t < 14; t += 4) {
        int mt = t & 1, nt = t >> 1;
        const short* ap = Alds + (mt * 16 + l16) * Astr + q * 8;
        const short* bp = Bg + (size_t)(nt * 16 + l16) * Kpad + q * 8;
        float4v acc = {0.f, 0.f, 0.f, 0.f};
        for (int kt = 0; kt < ktiles; ++kt) {
            short8 a = *(const short8*)(ap + kt * 32);
            short8 b = *(const short8*)(bp + kt * 32);
            acc = __builtin_amdgcn_mfma_f32_16x16x32_bf16(a, b, acc, 0, 0, 0);
        }
        int j = nt * 16 + l16;
        if (j < 100) {
            float bj = bias ? bias[j] : 0.f;
            int ebase = mt * 16 + q * 4;
            if (outA) {
                for (int r = 0; r < 4; ++r) {
                    float v = fmaxf(acc[r] + bj, 0.f);
                    outA[(ebase + r) * outAstr + j] = f2bf(v);
                }
            } else {
                float part = 0.f;
                for (int r = 0; r < 4; ++r) part += maskf[ebase + r] * (acc[r] + bj);
                atomicAdd(&Sred[j], part);
            }
        }
    }
}

// ---------------------------------------------------------------------------
// prep (round-9 verbatim): wt1 [112][192], wt2/wt3 [112][128].
// ---------------------------------------------------------------------------
__global__ __launch_bounds__(NT) void prep_w(P28 p)
{
    int id = blockIdx.x * NT + threadIdx.x;
    int stride = gridDim.x * NT;
    for (int i = id; i < 112 * 192; i += stride) {
        int n = i / 192, k = i - n * 192;
        float v = 0.f;
        if (n < 100) {
            int row = -1;
            if (k < 132) row = 100 + k;
            else if (k < 165) row = 232 + (k - 132);
            if (row >= 0) v = p.w1s[(size_t)row * 100 + n];
        }
        p.wt1[i] = f2bf(v);
    }
    for (int i = id; i < 112 * 128; i += stride) {
        int n = i / 128, k = i - n * 128;
        p.wt2[i] = f2bf((n < 100 && k < 116) ? p.w2s[(size_t)k * 100 + n] : 0.f);
    }
    for (int i = id; i < 112 * 128; i += stride) {
        int n = i / 128, k = i - n * 128;
        p.wt3[i] = f2bf((n < 100 && k < 116) ? p.w3s[(size_t)k * 100 + n] : 0.f);
    }
}

// ---------------------------------------------------------------------------
// Edge kernel v4: one block per node; 30 edges (+2 pad). ~16 barrier phases
// (was ~28). All v-path weights (2,740 fp32 = 10.9 KB) staged ONCE into a
// persistent LDS cache `wc` in the opening phase; every v-path gemm is then
// compute->sync->store (gemm_c) with zero global traffic. vn passes merged
// into the following gemm_c phase (its internal barrier fences both).
// wc layout (floats): w1h padded [33][36] @0, w1v [33][16] @1188,
// w2h @1716, w2v @1972, w3h @2228, w3v @2484 ([16][16] each).
// LDS total 46,064 B -> 3 blocks/CU (unchanged from measured residency).
// ---------------------------------------------------------------------------
__global__ __launch_bounds__(NT) void edge_kernel(P28 p)
{
    __shared__ __align__(16) short A1s[32 * 200];     // 12,800 B; later A3 [32][136]
    __shared__ __align__(16) float vhb[33 * 96];      // 12,672 B vbuf -> vh -> v ping-pong
    __shared__ __align__(16) short A2s[32 * 136];     //  8,704 B
    __shared__ __align__(16) float wc[2740];          // 10,960 B persistent v-path weights
    __shared__ float Sred[100];                       //    400 B fused s-mean accumulator
    __shared__ float ubias[100];                      //    400 B GEMM1 fused bias
    __shared__ float maskf[32];                       //    128 B

    short* A3s = A1s;   // [32][136] = 8,704 B <= A1s

    const int node = blockIdx.x, tid = threadIdx.x;
    const float* hV = p.h_V + (size_t)node * 148;

    // ================= staging phase (one barrier) =================
    for (int i = tid; i < 32; i += NT)
        maskf[i] = (i < 30) ? (float)p.mask_attend[(size_t)node * 30 + i] : 0.f;
    for (int i = tid; i < 100; i += NT) Sred[i] = 0.f;
    // A1 cols 0..131: hM scalars bf16
    for (int idx = tid; idx < 32 * 132; idx += NT) {
        int e = idx / 132, k = idx - e * 132;
        float v = (e < 30) ? p.h_M[((size_t)node * 30 + e) * 183 + 51 + k] : 0.f;
        A1s[e * 200 + k] = f2bf(v);
    }
    // A1 cols 165..191: zero K pad
    for (int idx = tid; idx < 32 * 27; idx += NT) {
        int kk = idx >> 5, e = idx & 31;
        A1s[e * 200 + 165 + kk] = 0;
    }
    // A2 pad cols 116..127
    for (int idx = tid; idx < 32 * 12; idx += NT) {
        int kk = idx >> 5, e = idx & 31;
        A2s[e * 136 + 116 + kk] = 0;
    }
    // vbuf fp32 vectors [i][c*32+e]
    for (int idx = tid; idx < 33 * 96; idx += NT) {
        int i = idx / 96, r = idx - i * 96, c = r >> 5, e = r & 31;
        float v = 0.f;
        if (i < 16) v = hV[c * 16 + i];
        else if (e < 30) v = p.h_M[((size_t)node * 30 + e) * 183 + c * 17 + (i - 16)];
        vhb[idx] = v;
    }
    // persistent weight cache
    for (int i = tid; i < 33 * 36; i += NT) {           // w1h padded [33][36]
        int k = i / 36, j = i - k * 36;
        wc[i] = (j < 33) ? p.w1h[(size_t)k * 33 + j] : 0.f;
    }
    for (int i = tid; i < 528; i += NT) wc[1188 + i] = p.w1v[i];
    for (int i = tid; i < 256; i += NT) wc[1716 + i] = p.w2h[i];
    for (int i = tid; i < 256; i += NT) wc[1972 + i] = p.w2v[i];
    for (int i = tid; i < 256; i += NT) wc[2228 + i] = p.w3h[i];
    for (int i = tid; i < 256; i += NT) wc[2484 + i] = p.w3v[i];
    // ubias[j] = b1[j] + sum_i hVs[i] * w1s[i][j] (rank-1 fold, fp32)
    for (int j = tid; j < 100; j += NT) {
        float s = p.b1[j];
        for (int i = 0; i < 100; ++i)
            s = fmaf(hV[48 + i], p.w1s[(size_t)i * 100 + j], s);
        ubias[j] = s;
    }
    __syncthreads();

    // P1: vh1 = vbuf @ w1h (IN PLACE; internal sync precedes stores)
    gemm_c(vhb, 33, wc, 36, 36, 33, vhb, 96, tid);
    __syncthreads();
    // P2: vn1 -> A1 cols 132..164  ||  v1 = vh1 @ w1v -> vhb rows 0..15
    for (int idx = tid; idx < 33 * 32; idx += NT) {
        int h = idx >> 5, e = idx & 31;
        float a = vhb[h * 96 + e], b = vhb[h * 96 + 32 + e], c = vhb[h * 96 + 64 + e];
        A1s[e * 200 + 132 + h] = f2bf(sqrtf(fmaxf(a * a + b * b + c * c, 1e-8f)));
    }
    gemm_c(vhb, 33, wc + 1188, 16, 16, 16, vhb, 96, tid);
    __syncthreads();
    // P3: gate(v1) || GEMM1: s1 = relu(A1 @ wt1 + ubias) -> A2
    gate_dev(vhb, 16, 96, 32, tid);
    mfma_gemm(A1s, 200, p.wt1, 192, 6, ubias, A2s, 136, nullptr, nullptr, tid);
    __syncthreads();

    // P4: vh2 = v1 @ w2h -> vhb rows 16..31
    gemm_c(vhb, 16, wc + 1716, 16, 16, 16, vhb + 16 * 96, 96, tid);
    __syncthreads();
    // P5: vn2 -> A2 cols 100..115 + A3 pad  ||  v2 = vh2 @ w2v -> rows 0..15
    for (int idx = tid; idx < 16 * 32; idx += NT) {
        int h = idx >> 5, e = idx & 31;
        float a = vhb[(16 + h) * 96 + e], b = vhb[(16 + h) * 96 + 32 + e], c = vhb[(16 + h) * 96 + 64 + e];
        A2s[e * 136 + 100 + h] = f2bf(sqrtf(fmaxf(a * a + b * b + c * c, 1e-8f)));
    }
    for (int idx = tid; idx < 32 * 12; idx += NT) {
        int kk = idx >> 5, e = idx & 31;
        A3s[e * 136 + 116 + kk] = 0;
    }
    gemm_c(vhb + 16 * 96, 16, wc + 1972, 16, 16, 16, vhb, 96, tid);
    __syncthreads();
    // P6: gate(v2) || GEMM2: s2 = relu(A2 @ wt2 + b2) -> A3
    gate_dev(vhb, 16, 96, 32, tid);
    mfma_gemm(A2s, 136, p.wt2, 128, 4, p.b2, A3s, 136, nullptr, nullptr, tid);
    __syncthreads();

    // P7: vh3 = v2 @ w3h -> rows 16..31
    gemm_c(vhb, 16, wc + 2228, 16, 16, 16, vhb + 16 * 96, 96, tid);
    __syncthreads();
    // P8: vn3 -> A3 cols 100..115  ||  v3 = vh3 @ w3v -> rows 0..15 (no gate)
    for (int idx = tid; idx < 16 * 32; idx += NT) {
        int h = idx >> 5, e = idx & 31;
        float a = vhb[(16 + h) * 96 + e], b = vhb[(16 + h) * 96 + 32 + e], c = vhb[(16 + h) * 96 + 64 + e];
        A3s[e * 136 + 100 + h] = f2bf(sqrtf(fmaxf(a * a + b * b + c * c, 1e-8f)));
    }
    gemm_c(vhb + 16 * 96, 16, wc + 2484, 16, 16, 16, vhb, 96, tid);
    __syncthreads();
    // P9: GEMM3: s3 = A3 @ wt3 + b3, fused masked edge-sum -> Sred
    mfma_gemm(A3s, 136, p.wt3, 128, 4, p.b3, nullptr, 0, Sred, maskf, tid);
    __syncthreads();

    // P10: dh = masked mean (vector part from vhb rows 0..15, scalars Sred)
    float* dhn = p.dh + (size_t)node * 148;
    for (int f = tid; f < 148; f += NT) {
        float s;
        if (f < 48) {
            int c = f >> 4, o = f & 15;
            const float* src = vhb + o * 96 + c * 32;
            float acc = 0.f;
            int e = f % 30;
            for (int t = 0; t < 30; ++t) { acc += maskf[e] * src[e]; if (++e == 30) e = 0; }
            s = acc;
        } else {
            s = Sred[f - 48];
        }
        dhn[f] = s * (1.f / 30.f);
    }
}

// ---------------------------------------------------------------------------
// Node kernel: 16 nodes per block (round-0 verbatim — best measured config).
// ---------------------------------------------------------------------------
__global__ __launch_bounds__(NT) void node_kernel(P28 p)
{
    __shared__ __align__(16) float Bbuf[3200];
    __shared__ __align__(16) float S1n[132 * 16];
    __shared__ __align__(16) float A2n[400 * 16];
    __shared__ __align__(16) float s2n[100 * 16];
    __shared__ __align__(16) float hvv[16 * 48];
    __shared__ __align__(16) float vhA[32 * 48];
    __shared__ __align__(16) float vhB[32 * 48];
    __shared__ float mu[16], isd[16], vrm[16], mkv[16];

    const int nb = blockIdx.x * 16;
    const int tid = threadIdx.x;

    for (int idx = tid; idx < 1600; idx += NT) {
        int n = idx & 15, j = idx >> 4;
        size_t g = (size_t)(nb + n) * 148 + 48 + j;
        S1n[idx] = p.h_V[g] + p.dh[g];
    }
    for (int idx = tid; idx < 768; idx += NT) {
        int i = idx / 48, r = idx - i * 48, c = r >> 4, n = r & 15;
        size_t g = (size_t)(nb + n) * 148 + c * 16 + i;
        hvv[idx] = p.h_V[g] + p.dh[g];
    }
    for (int i = tid; i < 16; i += NT) mkv[i] = (float)p.mask_V[nb + i];
    __syncthreads();

    if (tid < 16) {
        int n = tid;
        float sm = 0.f;
        for (int j = 0; j < 100; ++j) sm += S1n[j * 16 + n];
        float m = sm * 0.01f, var = 0.f;
        for (int j = 0; j < 100; ++j) { float d = S1n[j * 16 + n] - m; var += d * d; }
        mu[n] = m; isd[n] = rsqrtf(var * 0.01f + 1e-3f);
        float vm = 0.f;
        for (int i = 0; i < 16; ++i) {
            float a = hvv[i * 48 + n], b = hvv[i * 48 + 16 + n], c = hvv[i * 48 + 32 + n];
            vm += fmaxf(a * a + b * b + c * c, 1e-8f);
        }
        vrm[n] = rsqrtf(vm * (1.f / 16.f));
    }
    __syncthreads();
    for (int idx = tid; idx < 1600; idx += NT) {
        int n = idx & 15, j = idx >> 4;
        S1n[idx] = (S1n[idx] - mu[n]) * isd[n] * p.g1[j] + p.be1[j];
    }
    for (int idx = tid; idx < 768; idx += NT) hvv[idx] *= vrm[idx & 15];
    __syncthreads();

    gemm(hvv, 16, nullptr, 16, nullptr, 0, p.d1h, 32, 32, nullptr, false, vhA, 48, Bbuf, 3200, tid);
    __syncthreads();
    vn_dev(vhA, 32, 48, 16, S1n + 100 * 16, 16, tid);
    __syncthreads();
    gemm(S1n, 132, nullptr, 132, nullptr, 0, p.d1s,       400, 200, p.db1,       true, A2n,            16, Bbuf, 3200, tid);
    gemm(S1n, 132, nullptr, 132, nullptr, 0, p.d1s + 200, 400, 200, p.db1 + 200, true, A2n + 200 * 16, 16, Bbuf, 3200, tid);
    gemm(vhA, 32, nullptr, 32, nullptr, 0, p.d1v, 32, 32, nullptr, false, vhB, 48, Bbuf, 3200, tid);
    __syncthreads();
    gate_dev(vhB, 32, 48, 16, tid);
    __syncthreads();

    gemm(vhB, 32, nullptr, 32, nullptr, 0, p.d2h, 32, 32, nullptr, false, vhA, 48, Bbuf, 3200, tid);
    __syncthreads();
    vn_dev(vhA, 32, 48, 16, S1n + 100 * 16, 16, tid);
    __syncthreads();
    gemm(A2n, 400, S1n + 100 * 16, 432, nullptr, 0, p.d2s, 100, 100, p.db2, false, s2n, 16, Bbuf, 3200, tid);
    gemm(vhA, 32, nullptr, 32, nullptr, 0, p.d2v, 16, 16, nullptr, false, vhB, 48, Bbuf, 3200, tid);
    __syncthreads();

    for (int idx = tid; idx < 1600; idx += NT) s2n[idx] += S1n[idx];
    for (int idx = tid; idx < 768; idx += NT) vhB[idx] += hvv[idx];
    __syncthreads();

    if (tid < 16) {
        int n = tid;
        float sm = 0.f;
        for (int j = 0; j < 100; ++j) sm += s2n[j * 16 + n];
        float m = sm * 0.01f, var = 0.f;
        for (int j = 0; j < 100; ++j) { float d = s2n[j * 16 + n] - m; var += d * d; }
        mu[n] = m; isd[n] = rsqrtf(var * 0.01f + 1e-3f);
        float vm = 0.f;
        for (int i = 0; i < 16; ++i) {
            float a = vhB[i * 48 + n], b = vhB[i * 48 + 16 + n], c = vhB[i * 48 + 32 + n];
            vm += fmaxf(a * a + b * b + c * c, 1e-8f);
        }
        vrm[n] = rsqrtf(vm * (1.f / 16.f));
    }
    __syncthreads();
    for (int idx = tid; idx < 1600; idx += NT) {
        int n = idx & 15, j = idx >> 4;
        s2n[idx] = (s2n[idx] - mu[n]) * isd[n] * p.g2[j] + p.be2[j];
    }
    for (int idx = tid; idx < 768; idx += NT) vhB[idx] *= vrm[idx & 15];
    __syncthreads();

    for (int idx = tid; idx < 16 * 148; idx += NT) {
        int n = idx / 148, f = idx - n * 148;
        float v;
        if (f < 48) { int c = f >> 4, o = f & 15; v = vhB[o * 48 + c * 16 + n]; }
        else        { v = s2n[(f - 48) * 16 + n]; }
        p.out[(size_t)(nb + n) * 148 + f] = mkv[n] * v;
    }
}

extern "C" void kernel_launch(void* const* d_in, const int* in_sizes, int n_in,
                              void* d_out, int out_size, void* d_ws, size_t ws_size,
                              hipStream_t stream)
{
    P28 p;
    p.h_V = (const float*)d_in[0];
    p.h_M = (const float*)d_in[1];
    p.mask_V = (const int*)d_in[2];
    p.mask_attend = (const int*)d_in[3];
    const float** w = (const float**)&p.w1h;
    for (int i = 0; i < 24; ++i) w[i] = (const float*)d_in[4 + i];
    p.out = (float*)d_out;
    p.dh  = (float*)d_out;              // stage dh in d_out; node kernel reads then overwrites
    p.wt1 = (short*)d_ws;               // 112*192 bf16
    p.wt2 = p.wt1 + 112 * 192;          // 112*128 bf16
    p.wt3 = p.wt2 + 112 * 128;          // 112*128 bf16

    prep_w<<<dim3(64), dim3(NT), 0, stream>>>(p);
    edge_kernel<<<dim3(8192), dim3(NT), 0, stream>>>(p);
    node_kernel<<<dim3(512),  dim3(NT), 0, stream>>>(p);
}